// Round 1
// baseline (1108.325 us; speedup 1.0000x reference)
//
#include <hip/hip_runtime.h>
#include <math.h>

#ifndef __has_builtin
#define __has_builtin(x) 0
#endif

#define B_   20
#define S_   500
#define DIM_ 300
#define QK_  128
#define HID_ 600
#define NROW (B_ * S_)   // 10000

// ---------- helpers ----------

__device__ __forceinline__ int dot4(int a, int b, int acc) {
#if __has_builtin(__builtin_amdgcn_sdot4)
  return __builtin_amdgcn_sdot4(a, b, acc, false);
#else
  acc += (int)(signed char)(a)       * (int)(signed char)(b);
  acc += (int)(signed char)(a >> 8)  * (int)(signed char)(b >> 8);
  acc += (int)(signed char)(a >> 16) * (int)(signed char)(b >> 16);
  acc += (int)(signed char)(a >> 24) * (int)(signed char)(b >> 24);
  return acc;
#endif
}

// T5 relative-position bucket. val_large = 8 + int(log(n/8)/log(16)*8) has
// exact integer thresholds at n = 8*2^(k/2): {12,16,23,32,46,64,91}; n>=91 -> 15
// (min with nb-1=15 also caps n>=128). Verified float boundary cases n=16/32/64/128.
__device__ __forceinline__ int t5_bucket(int i, int j) {
  int d = i - j;                 // reference: n = -(j - i)
  int ret = (d < 0) ? 16 : 0;
  int n = d < 0 ? -d : d;
  int v;
  if (n < 8)       v = n;
  else if (n < 12) v = 8;
  else if (n < 16) v = 9;
  else if (n < 23) v = 10;
  else if (n < 32) v = 11;
  else if (n < 46) v = 12;
  else if (n < 64) v = 13;
  else if (n < 91) v = 14;
  else             v = 15;
  return ret + v;
}

__device__ __forceinline__ float quant15(float y, float s) {
  return truncf(fminf(fmaxf(__fdiv_rn(y, s), -15.f), 15.f));
}

// ---------- kernel 1: layernorm ----------
__global__ __launch_bounds__(256) void k_ln(const float* __restrict__ x,
                                            const float* __restrict__ g,
                                            const float* __restrict__ b,
                                            float* __restrict__ normed) {
  int row = blockIdx.x;
  const float* xr = x + (size_t)row * DIM_;
  __shared__ float red[256];
  int tid = threadIdx.x;
  float s = 0.f;
  for (int c = tid; c < DIM_; c += 256) s += xr[c];
  red[tid] = s; __syncthreads();
  for (int off = 128; off > 0; off >>= 1) {
    if (tid < off) red[tid] += red[tid + off];
    __syncthreads();
  }
  float mu = red[0] / (float)DIM_;
  __syncthreads();
  float s2 = 0.f;
  for (int c = tid; c < DIM_; c += 256) { float d = xr[c] - mu; s2 += d * d; }
  red[tid] = s2; __syncthreads();
  for (int off = 128; off > 0; off >>= 1) {
    if (tid < off) red[tid] += red[tid + off];
    __syncthreads();
  }
  float var = red[0] / (float)DIM_;
  float denom = sqrtf(var + 1e-5f);
  for (int c = tid; c < DIM_; c += 256)
    normed[(size_t)row * DIM_ + c] = __fdiv_rn(xr[c] - mu, denom) * g[c] + b[c];
}

// ---------- kernel 2: token shift + dual row-quant ----------
__global__ __launch_bounds__(256) void k_shiftquant(
    const float* __restrict__ normed,
    const float* __restrict__ qk_s, const float* __restrict__ hidden_s,
    signed char* __restrict__ xq8, signed char* __restrict__ xh8,
    float* __restrict__ sq, float* __restrict__ sh) {
  int row = blockIdx.x;
  int s_idx = row % S_;
  int tid = threadIdx.x;
  __shared__ float redq[256], redh[256];
  float yq[2], yh[2];
  float mq = 0.f, mh = 0.f;
  #pragma unroll
  for (int it = 0; it < 2; ++it) {
    int c = tid + it * 256;
    if (c < DIM_) {
      float src;
      if (c < DIM_ / 2) src = (s_idx > 0) ? normed[(size_t)(row - 1) * DIM_ + c] : 0.f;
      else              src = normed[(size_t)row * DIM_ + c];
      yq[it] = __fdiv_rn(src, qk_s[c]);
      yh[it] = __fdiv_rn(src, hidden_s[c]);
      mq = fmaxf(mq, fabsf(yq[it]));
      mh = fmaxf(mh, fabsf(yh[it]));
    }
  }
  redq[tid] = mq; redh[tid] = mh; __syncthreads();
  for (int off = 128; off > 0; off >>= 1) {
    if (tid < off) {
      redq[tid] = fmaxf(redq[tid], redq[tid + off]);
      redh[tid] = fmaxf(redh[tid], redh[tid + off]);
    }
    __syncthreads();
  }
  float sqv = redq[0] / 15.0f, shv = redh[0] / 15.0f;
  if (tid == 0) { sq[row] = sqv; sh[row] = shv; }
  #pragma unroll
  for (int it = 0; it < 2; ++it) {
    int c = tid + it * 256;
    if (c < DIM_) {
      xq8[(size_t)row * DIM_ + c] = (signed char)quant15(yq[it], sqv);
      xh8[(size_t)row * DIM_ + c] = (signed char)quant15(yh[it], shv);
    }
  }
}

// ---------- kernel 3: hidden GEMM (10000x1200x300) + silu -> v, gate ----------
__global__ __launch_bounds__(256) void k_hidden(
    const signed char* __restrict__ xh8, const float* __restrict__ sh,
    const float* __restrict__ Wh, const float* __restrict__ bh,
    const float* __restrict__ hp,
    float* __restrict__ v, float* __restrict__ gate) {
  int row0 = blockIdx.x * 8;
  int tid = threadIdx.x;
  __shared__ __align__(16) float xs[DIM_][8];
  __shared__ float shv[8];
  for (int idx = tid; idx < 8 * DIM_; idx += 256) {
    int c = idx >> 3, r = idx & 7;
    xs[c][r] = (float)xh8[(size_t)(row0 + r) * DIM_ + c];
  }
  if (tid < 8) shv[tid] = sh[row0 + tid];
  __syncthreads();
  for (int cc = tid; cc < 2 * HID_; cc += 256) {
    const float* wc = Wh + (size_t)cc * DIM_;
    float acc[8] = {0, 0, 0, 0, 0, 0, 0, 0};
    for (int k = 0; k < DIM_; ++k) {
      float w = wc[k];
      const float4* a4 = (const float4*)&xs[k][0];
      float4 a0 = a4[0], a1 = a4[1];
      acc[0] += a0.x * w; acc[1] += a0.y * w; acc[2] += a0.z * w; acc[3] += a0.w * w;
      acc[4] += a1.x * w; acc[5] += a1.y * w; acc[6] += a1.z * w; acc[7] += a1.w * w;
    }
    float bc = bh[cc], hpc = hp[cc];
    #pragma unroll
    for (int r = 0; r < 8; ++r) {
      float z = acc[r] + bc;
      float sig = 1.0f / (1.0f + expf(-z));
      float val = __fmul_rn(z * sig, __fmul_rn(shv[r], hpc));
      if (cc < HID_) v[(size_t)(row0 + r) * HID_ + cc] = val;
      else           gate[(size_t)(row0 + r) * HID_ + (cc - HID_)] = val;
    }
  }
}

// ---------- kernel 4: qk GEMM + silu + scale + rotary + row-quant ----------
__global__ __launch_bounds__(128) void k_qk(
    const signed char* __restrict__ xq8, const float* __restrict__ sq,
    const float* __restrict__ Wqk, const float* __restrict__ bqk,
    const float* __restrict__ qkp, const float* __restrict__ osg,
    const float* __restrict__ osb,
    signed char* __restrict__ qq8, signed char* __restrict__ kq8,
    float* __restrict__ qs, float* __restrict__ ks) {
  int row = blockIdx.x;
  int pos = row % S_;
  int c = threadIdx.x;   // 0..127
  __shared__ __align__(16) float xs[DIM_];
  __shared__ float qbuf[QK_], kbuf[QK_];
  __shared__ float redq[QK_], redk[QK_];
  for (int idx = c; idx < DIM_; idx += 128)
    xs[idx] = (float)xq8[(size_t)row * DIM_ + idx];
  __syncthreads();
  const float4* wc4 = (const float4*)(Wqk + (size_t)c * DIM_);
  float acc = 0.f;
  for (int k4 = 0; k4 < DIM_ / 4; ++k4) {
    float4 wv = wc4[k4];
    float4 xv = *(const float4*)&xs[k4 * 4];
    acc += xv.x * wv.x; acc += xv.y * wv.y; acc += xv.z * wv.z; acc += xv.w * wv.w;
  }
  float z = acc + bqk[c];
  float sig = 1.0f / (1.0f + expf(-z));
  float qkv = __fmul_rn(z * sig, __fmul_rn(sq[row], qkp[c]));
  float qv = __fadd_rn(__fmul_rn(qkv, osg[c]),       osb[c]);
  float kv = __fadd_rn(__fmul_rn(qkv, osg[QK_ + c]), osb[QK_ + c]);
  qbuf[c] = qv; kbuf[c] = kv;
  __syncthreads();
  if (c < 32) {
    double e = (double)(c & ~1) / 32.0;          // (2j)/32
    float inv = (float)(1.0 / pow(10000.0, e));
    float fr = __fmul_rn((float)pos, inv);
    float cs = cosf(fr), sn = sinf(fr);
    float rq = ((c & 1) == 0) ? -qbuf[c + 1] : qbuf[c - 1];
    float rk = ((c & 1) == 0) ? -kbuf[c + 1] : kbuf[c - 1];
    qv = __fadd_rn(__fmul_rn(qv, cs), __fmul_rn(rq, sn));
    kv = __fadd_rn(__fmul_rn(kv, cs), __fmul_rn(rk, sn));
  }
  redq[c] = fabsf(qv); redk[c] = fabsf(kv);
  __syncthreads();
  for (int off = 64; off > 0; off >>= 1) {
    if (c < off) {
      redq[c] = fmaxf(redq[c], redq[c + off]);
      redk[c] = fmaxf(redk[c], redk[c + off]);
    }
    __syncthreads();
  }
  float qsv = redq[0] / 15.0f, ksv = redk[0] / 15.0f;
  if (c == 0) { qs[row] = qsv; ks[row] = ksv; }
  qq8[(size_t)row * QK_ + c] = (signed char)quant15(qv, qsv);
  kq8[(size_t)row * QK_ + c] = (signed char)quant15(kv, ksv);
}

// ---------- kernel 5: integer QK^T + T5 bias + relu^2 + row-quant ----------
__global__ __launch_bounds__(256) void k_sim(
    const signed char* __restrict__ qq8, const signed char* __restrict__ kq8,
    const float* __restrict__ qs, const float* __restrict__ ks,
    const float* __restrict__ rel_emb,
    signed char* __restrict__ aq8, float* __restrict__ as_) {
  int blk = blockIdx.x;
  int b = blk / S_, i = blk % S_;
  int tid = threadIdx.x;
  __shared__ int qrow[32];      // 128 int8 packed
  __shared__ float rel[32];
  __shared__ float red[256];
  if (tid < 32) {
    qrow[tid] = ((const int*)(qq8 + (size_t)blk * QK_))[tid];
    rel[tid] = rel_emb[tid];
  }
  __syncthreads();
  float qsv = qs[blk];
  float av[2] = {0.f, 0.f};
  #pragma unroll
  for (int it = 0; it < 2; ++it) {
    int j = tid + it * 256;
    if (j < S_) {
      const int4* kp4 = (const int4*)(kq8 + (size_t)(b * S_ + j) * QK_);
      int acc = 0;
      #pragma unroll
      for (int w = 0; w < 8; ++w) {
        int4 kv4 = kp4[w];
        acc = dot4(qrow[4 * w + 0], kv4.x, acc);
        acc = dot4(qrow[4 * w + 1], kv4.y, acc);
        acc = dot4(qrow[4 * w + 2], kv4.z, acc);
        acc = dot4(qrow[4 * w + 3], kv4.w, acc);
      }
      float simv = __fmul_rn(__fmul_rn((float)acc, qsv), ks[b * S_ + j]);
      simv = __fadd_rn(simv, __fmul_rn(rel[t5_bucket(i, j)], 11.313708498984761f));
      float r = fmaxf(__fdiv_rn(simv, 500.0f), 0.f);
      av[it] = __fmul_rn(r, r);
    }
  }
  float m = fmaxf(av[0], av[1]);
  red[tid] = m; __syncthreads();
  for (int off = 128; off > 0; off >>= 1) {
    if (tid < off) red[tid] = fmaxf(red[tid], red[tid + off]);
    __syncthreads();
  }
  float asv = red[0] / 15.0f;
  if (tid == 0) as_[blk] = asv;
  #pragma unroll
  for (int it = 0; it < 2; ++it) {
    int j = tid + it * 256;
    if (j < S_)
      aq8[(size_t)blk * S_ + j] = (signed char)quant15(av[it], asv);
  }
}

// ---------- kernel 6: quantize v over axis=1 (per b, per d), transposed out ----------
__global__ __launch_bounds__(256) void k_vq(const float* __restrict__ v,
                                            signed char* __restrict__ vq8t,
                                            float* __restrict__ vs) {
  int d = blockIdx.x * 256 + threadIdx.x;
  int b = blockIdx.y;
  if (d >= HID_) return;
  const float* vp = v + (size_t)b * S_ * HID_ + d;
  float m = 0.f;
  for (int s = 0; s < S_; ++s) m = fmaxf(m, fabsf(vp[(size_t)s * HID_]));
  float vsv = m / 15.0f;
  vs[b * HID_ + d] = vsv;
  signed char* o = vq8t + ((size_t)b * HID_ + d) * 512;
  for (int s = 0; s < S_; ++s)
    o[s] = (signed char)quant15(vp[(size_t)s * HID_], vsv);
  for (int s = S_; s < 512; ++s) o[s] = 0;
}

// ---------- kernel 7: integer PV + gate + /out_s + row-quant ----------
__global__ __launch_bounds__(256) void k_pv(
    const signed char* __restrict__ aq8, const float* __restrict__ as_,
    const signed char* __restrict__ vq8t, const float* __restrict__ vs,
    const float* __restrict__ gate, const float* __restrict__ out_s,
    signed char* __restrict__ oq8, float* __restrict__ osc) {
  int blk = blockIdx.x;
  int b = blk / S_;
  int tid = threadIdx.x;
  __shared__ int arow[128];     // 500 bytes padded to 512
  __shared__ float red[256];
  if (tid < 128) {
    int w = 0;
    if (tid < 125) w = ((const int*)(aq8 + (size_t)blk * S_))[tid];
    arow[tid] = w;
  }
  __syncthreads();
  float asv = as_[blk];
  float ov[3];
  float m = 0.f;
  #pragma unroll
  for (int it = 0; it < 3; ++it) {
    int c = tid + it * 256;
    ov[it] = 0.f;
    if (c < HID_) {
      const int4* vp4 = (const int4*)(vq8t + ((size_t)b * HID_ + c) * 512);
      int acc = 0;
      #pragma unroll 8
      for (int w = 0; w < 32; ++w) {
        int4 vv = vp4[w];
        acc = dot4(arow[4 * w + 0], vv.x, acc);
        acc = dot4(arow[4 * w + 1], vv.y, acc);
        acc = dot4(arow[4 * w + 2], vv.z, acc);
        acc = dot4(arow[4 * w + 3], vv.w, acc);
      }
      float o = __fmul_rn(__fmul_rn((float)acc, asv), vs[b * HID_ + c]);
      o = __fmul_rn(o, gate[(size_t)blk * HID_ + c]);
      o = __fdiv_rn(o, out_s[c]);
      ov[it] = o;
      m = fmaxf(m, fabsf(o));
    }
  }
  red[tid] = m; __syncthreads();
  for (int off = 128; off > 0; off >>= 1) {
    if (tid < off) red[tid] = fmaxf(red[tid], red[tid + off]);
    __syncthreads();
  }
  float oscv = red[0] / 15.0f;
  if (tid == 0) osc[blk] = oscv;
  #pragma unroll
  for (int it = 0; it < 3; ++it) {
    int c = tid + it * 256;
    if (c < HID_)
      oq8[(size_t)blk * HID_ + c] = (signed char)quant15(ov[it], oscv);
  }
}

// ---------- kernel 8: output GEMM (10000x300x600) + residual ----------
__global__ __launch_bounds__(256) void k_final(
    const signed char* __restrict__ oq8, const float* __restrict__ osc,
    const float* __restrict__ Wo, const float* __restrict__ bo,
    const float* __restrict__ op, const float* __restrict__ x,
    float* __restrict__ out) {
  int row0 = blockIdx.x * 8;
  int tid = threadIdx.x;
  __shared__ __align__(16) float os2[HID_][8];
  __shared__ float oscv[8];
  for (int idx = tid; idx < 8 * HID_; idx += 256) {
    int c = idx >> 3, r = idx & 7;
    os2[c][r] = (float)oq8[(size_t)(row0 + r) * HID_ + c];
  }
  if (tid < 8) oscv[tid] = osc[row0 + tid];
  __syncthreads();
  for (int cc = tid; cc < DIM_; cc += 256) {
    const float* wc = Wo + (size_t)cc * HID_;
    float acc[8] = {0, 0, 0, 0, 0, 0, 0, 0};
    for (int k = 0; k < HID_; ++k) {
      float w = wc[k];
      const float4* a4 = (const float4*)&os2[k][0];
      float4 a0 = a4[0], a1 = a4[1];
      acc[0] += a0.x * w; acc[1] += a0.y * w; acc[2] += a0.z * w; acc[3] += a0.w * w;
      acc[4] += a1.x * w; acc[5] += a1.y * w; acc[6] += a1.z * w; acc[7] += a1.w * w;
    }
    float bc = bo[cc], opc = op[cc];
    #pragma unroll
    for (int r = 0; r < 8; ++r) {
      float t = __fmul_rn(oscv[r], opc);
      float res = __fmul_rn(acc[r] + bc, t);
      out[(size_t)(row0 + r) * DIM_ + cc] = res + x[(size_t)(row0 + r) * DIM_ + cc];
    }
  }
}

// ---------- launch ----------
extern "C" void kernel_launch(void* const* d_in, const int* in_sizes, int n_in,
                              void* d_out, int out_size, void* d_ws, size_t ws_size,
                              hipStream_t stream) {
  const float* x        = (const float*)d_in[0];
  const float* ng       = (const float*)d_in[1];
  const float* nbt      = (const float*)d_in[2];
  const float* Wh       = (const float*)d_in[3];
  const float* bh       = (const float*)d_in[4];
  const float* Wqk      = (const float*)d_in[5];
  const float* bqk      = (const float*)d_in[6];
  const float* osg      = (const float*)d_in[7];
  const float* osb      = (const float*)d_in[8];
  const float* Wo       = (const float*)d_in[9];
  const float* bo       = (const float*)d_in[10];
  const float* rel      = (const float*)d_in[11];
  const float* qk_s     = (const float*)d_in[12];
  const float* hidden_s = (const float*)d_in[13];
  const float* out_s    = (const float*)d_in[14];
  const float* hp       = (const float*)d_in[15];
  const float* qkp      = (const float*)d_in[16];
  const float* op       = (const float*)d_in[17];
  float* out = (float*)d_out;

  char* ws = (char*)d_ws;
  size_t off = 0;
  auto alloc = [&](size_t bytes) {
    void* p = ws + off;
    off += (bytes + 255) & ~(size_t)255;
    return p;
  };
  float*       normed = (float*)      alloc((size_t)NROW * DIM_ * 4);
  signed char* xq8    = (signed char*)alloc((size_t)NROW * DIM_);
  signed char* xh8    = (signed char*)alloc((size_t)NROW * DIM_);
  float*       sq     = (float*)      alloc((size_t)NROW * 4);
  float*       sh     = (float*)      alloc((size_t)NROW * 4);
  float*       v      = (float*)      alloc((size_t)NROW * HID_ * 4);
  float*       gate   = (float*)      alloc((size_t)NROW * HID_ * 4);
  signed char* qq8    = (signed char*)alloc((size_t)NROW * QK_);
  signed char* kq8    = (signed char*)alloc((size_t)NROW * QK_);
  float*       qs     = (float*)      alloc((size_t)NROW * 4);
  float*       ks     = (float*)      alloc((size_t)NROW * 4);
  signed char* aq8    = (signed char*)alloc((size_t)NROW * S_);
  float*       as_    = (float*)      alloc((size_t)NROW * 4);
  signed char* vq8t   = (signed char*)alloc((size_t)B_ * HID_ * 512);
  float*       vs     = (float*)      alloc((size_t)B_ * HID_ * 4);
  signed char* oq8    = (signed char*)alloc((size_t)NROW * HID_);
  float*       osc    = (float*)      alloc((size_t)NROW * 4);

  k_ln<<<NROW, 256, 0, stream>>>(x, ng, nbt, normed);
  k_shiftquant<<<NROW, 256, 0, stream>>>(normed, qk_s, hidden_s, xq8, xh8, sq, sh);
  k_hidden<<<NROW / 8, 256, 0, stream>>>(xh8, sh, Wh, bh, hp, v, gate);
  k_qk<<<NROW, 128, 0, stream>>>(xq8, sq, Wqk, bqk, qkp, osg, osb, qq8, kq8, qs, ks);
  k_sim<<<NROW, 256, 0, stream>>>(qq8, kq8, qs, ks, rel, aq8, as_);
  k_vq<<<dim3((HID_ + 255) / 256, B_), 256, 0, stream>>>(v, vq8t, vs);
  k_pv<<<NROW, 256, 0, stream>>>(aq8, as_, vq8t, vs, gate, out_s, oq8, osc);
  k_final<<<NROW / 8, 256, 0, stream>>>(oq8, osc, Wo, bo, op, x, out);
}

// Round 2
// 566.446 us; speedup vs baseline: 1.9566x; 1.9566x over previous
//
#include <hip/hip_runtime.h>
#include <math.h>

#define B_   20
#define S_   500
#define DIM_ 300
#define QK_  128
#define HID_ 600
#define NROW (B_ * S_)   // 10000

typedef int v4i __attribute__((ext_vector_type(4)));

// T5 bucket: val_large = 8 + int(log(n/8)/log(16)*8) has exact integer
// thresholds {12,16,23,32,46,64,91}; >=91 -> 15.
__device__ __forceinline__ int t5_bucket(int i, int j) {
  int d = i - j;
  int ret = (d < 0) ? 16 : 0;
  int n = d < 0 ? -d : d;
  int v;
  if (n < 8)       v = n;
  else if (n < 12) v = 8;
  else if (n < 16) v = 9;
  else if (n < 23) v = 10;
  else if (n < 32) v = 11;
  else if (n < 46) v = 12;
  else if (n < 64) v = 13;
  else if (n < 91) v = 14;
  else             v = 15;
  return ret + v;
}

__device__ __forceinline__ float quant15(float y, float s) {
  return truncf(fminf(fmaxf(__fdiv_rn(y, s), -15.f), 15.f));
}

// ---------- transpose: src[R][C] -> dst[C][R] ----------
__global__ __launch_bounds__(256) void k_transpose(const float* __restrict__ src,
                                                   float* __restrict__ dst,
                                                   int R, int C) {
  int idx = blockIdx.x * 256 + threadIdx.x;
  if (idx < R * C) {
    int r = idx / C, c = idx % C;
    dst[(size_t)c * R + r] = src[idx];
  }
}

// ---------- kernel 1: layernorm ----------
__global__ __launch_bounds__(256) void k_ln(const float* __restrict__ x,
                                            const float* __restrict__ g,
                                            const float* __restrict__ b,
                                            float* __restrict__ normed) {
  int row = blockIdx.x;
  const float* xr = x + (size_t)row * DIM_;
  __shared__ float red[256];
  int tid = threadIdx.x;
  float s = 0.f;
  for (int c = tid; c < DIM_; c += 256) s += xr[c];
  red[tid] = s; __syncthreads();
  for (int off = 128; off > 0; off >>= 1) {
    if (tid < off) red[tid] += red[tid + off];
    __syncthreads();
  }
  float mu = red[0] / (float)DIM_;
  __syncthreads();
  float s2 = 0.f;
  for (int c = tid; c < DIM_; c += 256) { float d = xr[c] - mu; s2 += d * d; }
  red[tid] = s2; __syncthreads();
  for (int off = 128; off > 0; off >>= 1) {
    if (tid < off) red[tid] += red[tid + off];
    __syncthreads();
  }
  float var = red[0] / (float)DIM_;
  float denom = sqrtf(var + 1e-5f);
  for (int c = tid; c < DIM_; c += 256)
    normed[(size_t)row * DIM_ + c] = __fdiv_rn(xr[c] - mu, denom) * g[c] + b[c];
}

// ---------- kernel 2: token shift + dual row-quant ----------
__global__ __launch_bounds__(256) void k_shiftquant(
    const float* __restrict__ normed,
    const float* __restrict__ qk_s, const float* __restrict__ hidden_s,
    signed char* __restrict__ xq8, signed char* __restrict__ xh8,
    float* __restrict__ sq, float* __restrict__ sh) {
  int row = blockIdx.x;
  int s_idx = row % S_;
  int tid = threadIdx.x;
  __shared__ float redq[256], redh[256];
  float yq[2], yh[2];
  float mq = 0.f, mh = 0.f;
  #pragma unroll
  for (int it = 0; it < 2; ++it) {
    int c = tid + it * 256;
    if (c < DIM_) {
      float src;
      if (c < DIM_ / 2) src = (s_idx > 0) ? normed[(size_t)(row - 1) * DIM_ + c] : 0.f;
      else              src = normed[(size_t)row * DIM_ + c];
      yq[it] = __fdiv_rn(src, qk_s[c]);
      yh[it] = __fdiv_rn(src, hidden_s[c]);
      mq = fmaxf(mq, fabsf(yq[it]));
      mh = fmaxf(mh, fabsf(yh[it]));
    }
  }
  redq[tid] = mq; redh[tid] = mh; __syncthreads();
  for (int off = 128; off > 0; off >>= 1) {
    if (tid < off) {
      redq[tid] = fmaxf(redq[tid], redq[tid + off]);
      redh[tid] = fmaxf(redh[tid], redh[tid + off]);
    }
    __syncthreads();
  }
  float sqv = redq[0] / 15.0f, shv = redh[0] / 15.0f;
  if (tid == 0) { sq[row] = sqv; sh[row] = shv; }
  #pragma unroll
  for (int it = 0; it < 2; ++it) {
    int c = tid + it * 256;
    if (c < DIM_) {
      xq8[(size_t)row * DIM_ + c] = (signed char)quant15(yq[it], sqv);
      xh8[(size_t)row * DIM_ + c] = (signed char)quant15(yh[it], shv);
    }
  }
}

// ---------- kernel 3: hidden GEMM (W^T coalesced, 12 rows/block) ----------
#define HR 12
__global__ __launch_bounds__(256) void k_hidden(
    const signed char* __restrict__ xh8, const float* __restrict__ sh,
    const float* __restrict__ whT,   // [300][1200]
    const float* __restrict__ bh, const float* __restrict__ hp,
    float* __restrict__ v, float* __restrict__ gate) {
  int row0 = blockIdx.x * HR;
  int tid = threadIdx.x;
  __shared__ __align__(16) float xs[DIM_][HR];
  __shared__ float shv[HR];
  for (int idx = tid; idx < HR * DIM_; idx += 256) {
    int r = idx / DIM_, cc = idx % DIM_;
    int grow = row0 + r; if (grow > NROW - 1) grow = NROW - 1;
    xs[cc][r] = (float)xh8[(size_t)grow * DIM_ + cc];
  }
  if (tid < HR) {
    int grow = row0 + tid; if (grow > NROW - 1) grow = NROW - 1;
    shv[tid] = sh[grow];
  }
  __syncthreads();
  float acc[5][HR];
  #pragma unroll
  for (int m = 0; m < 5; ++m)
    #pragma unroll
    for (int r = 0; r < HR; ++r) acc[m][r] = 0.f;
  for (int k = 0; k < DIM_; ++k) {
    const float4* xp = (const float4*)&xs[k][0];
    float4 a0 = xp[0], a1 = xp[1], a2 = xp[2];
    float xv[HR] = {a0.x, a0.y, a0.z, a0.w, a1.x, a1.y, a1.z, a1.w,
                    a2.x, a2.y, a2.z, a2.w};
    #pragma unroll
    for (int m = 0; m < 5; ++m) {
      int cc = tid + m * 256;
      int ccl = cc < 2 * HID_ ? cc : 2 * HID_ - 1;
      float w = whT[(size_t)k * (2 * HID_) + ccl];
      #pragma unroll
      for (int r = 0; r < HR; ++r) acc[m][r] += xv[r] * w;
    }
  }
  #pragma unroll
  for (int m = 0; m < 5; ++m) {
    int cc = tid + m * 256;
    if (cc >= 2 * HID_) continue;
    float bc = bh[cc], hpc = hp[cc];
    #pragma unroll
    for (int r = 0; r < HR; ++r) {
      int grow = row0 + r;
      if (grow > NROW - 1) continue;
      float z = acc[m][r] + bc;
      float sig = 1.0f / (1.0f + expf(-z));
      float val = __fmul_rn(z * sig, __fmul_rn(shv[r], hpc));
      if (cc < HID_) v[(size_t)grow * HID_ + cc] = val;
      else           gate[(size_t)grow * HID_ + (cc - HID_)] = val;
    }
  }
}

// ---------- kernel 4: qk GEMM (W^T, 4 rows/block) + silu + rotary + quant ----------
__global__ __launch_bounds__(128) void k_qk(
    const signed char* __restrict__ xq8, const float* __restrict__ sq,
    const float* __restrict__ wqkT,   // [300][128]
    const float* __restrict__ bqk,
    const float* __restrict__ qkp, const float* __restrict__ osg,
    const float* __restrict__ osb,
    signed char* __restrict__ qq8, signed char* __restrict__ kq8,
    float* __restrict__ qs, float* __restrict__ ks) {
  int row0 = blockIdx.x * 4;
  int c = threadIdx.x;   // 0..127
  __shared__ float xs[4][DIM_];
  __shared__ float qbuf[4][QK_], kbuf[4][QK_];
  __shared__ float redq[4][QK_], redk[4][QK_];
  for (int idx = c; idx < 4 * DIM_; idx += 128) {
    int r = idx / DIM_, cc = idx % DIM_;
    xs[r][cc] = (float)xq8[(size_t)(row0 + r) * DIM_ + cc];
  }
  __syncthreads();
  float acc[4] = {0.f, 0.f, 0.f, 0.f};
  for (int k = 0; k < DIM_; ++k) {
    float w = wqkT[k * QK_ + c];
    #pragma unroll
    for (int r = 0; r < 4; ++r) acc[r] += xs[r][k] * w;
  }
  float bc = bqk[c], qkpc = qkp[c];
  float g0 = osg[c], g1 = osg[QK_ + c], b0 = osb[c], b1 = osb[QK_ + c];
  float qv[4], kv[4];
  #pragma unroll
  for (int r = 0; r < 4; ++r) {
    float z = acc[r] + bc;
    float sig = 1.0f / (1.0f + expf(-z));
    float qkv = __fmul_rn(z * sig, __fmul_rn(sq[row0 + r], qkpc));
    qv[r] = __fadd_rn(__fmul_rn(qkv, g0), b0);
    kv[r] = __fadd_rn(__fmul_rn(qkv, g1), b1);
    qbuf[r][c] = qv[r]; kbuf[r][c] = kv[r];
  }
  __syncthreads();
  if (c < 32) {
    double e = (double)(c & ~1) / 32.0;
    float inv = (float)(1.0 / pow(10000.0, e));
    #pragma unroll
    for (int r = 0; r < 4; ++r) {
      int pos = (row0 + r) % S_;
      float fr = __fmul_rn((float)pos, inv);
      float cs = cosf(fr), sn = sinf(fr);
      float rq = ((c & 1) == 0) ? -qbuf[r][c + 1] : qbuf[r][c - 1];
      float rk = ((c & 1) == 0) ? -kbuf[r][c + 1] : kbuf[r][c - 1];
      qv[r] = __fadd_rn(__fmul_rn(qv[r], cs), __fmul_rn(rq, sn));
      kv[r] = __fadd_rn(__fmul_rn(kv[r], cs), __fmul_rn(rk, sn));
    }
  }
  #pragma unroll
  for (int r = 0; r < 4; ++r) { redq[r][c] = fabsf(qv[r]); redk[r][c] = fabsf(kv[r]); }
  __syncthreads();
  for (int off = 64; off > 0; off >>= 1) {
    if (c < off) {
      #pragma unroll
      for (int r = 0; r < 4; ++r) {
        redq[r][c] = fmaxf(redq[r][c], redq[r][c + off]);
        redk[r][c] = fmaxf(redk[r][c], redk[r][c + off]);
      }
    }
    __syncthreads();
  }
  #pragma unroll
  for (int r = 0; r < 4; ++r) {
    float qsv = redq[r][0] / 15.0f, ksv = redk[r][0] / 15.0f;
    if (c == 0) { qs[row0 + r] = qsv; ks[row0 + r] = ksv; }
    qq8[(size_t)(row0 + r) * QK_ + c] = (signed char)quant15(qv[r], qsv);
    kq8[(size_t)(row0 + r) * QK_ + c] = (signed char)quant15(kv[r], ksv);
  }
}

// ---------- kernel 5: MFMA i8 QK^T + T5 bias + relu^2 + row-quant ----------
// block 256 (4 waves); block = 16 i-rows x 512 j; wave w owns j-tiles w*8..w*8+7
__global__ __launch_bounds__(256) void k_sim(
    const signed char* __restrict__ qq8,   // [NROW+16][128]
    const signed char* __restrict__ kq8,   // [NROW+16][128]
    const float* __restrict__ qs, const float* __restrict__ ks,  // padded
    const float* __restrict__ rel_emb,
    signed char* __restrict__ aq8,         // [NROW+16][512]
    float* __restrict__ as_) {
  int i0 = blockIdx.x * 16;
  int b = blockIdx.y;
  int tid = threadIdx.x;
  int w = tid >> 6, l = tid & 63, g = l >> 4, ln = l & 15;
  __shared__ __align__(16) signed char a_lds[16 * 144];
  __shared__ float rel[32];
  __shared__ int rowmax[16];
  if (tid < 128) {
    int r = tid >> 3, ww = tid & 7;
    *(v4i*)(a_lds + r * 144 + ww * 16) =
        *(const v4i*)(qq8 + ((size_t)(b * S_ + i0 + r)) * QK_ + ww * 16);
  }
  if (tid < 32) rel[tid] = rel_emb[tid];
  if (tid < 16) rowmax[tid] = 0;
  __syncthreads();
  v4i acc[8];
  v4i zero = {0, 0, 0, 0};
  #pragma unroll
  for (int t = 0; t < 8; ++t) acc[t] = zero;
  #pragma unroll
  for (int kk = 0; kk < 2; ++kk) {
    v4i afrag = *(const v4i*)(a_lds + ln * 144 + kk * 64 + g * 16);
    #pragma unroll
    for (int t = 0; t < 8; ++t) {
      int j0 = (w * 8 + t) * 16;
      v4i bfrag = *(const v4i*)(kq8 + ((size_t)(b * S_ + j0 + ln)) * QK_ + kk * 64 + g * 16);
      acc[t] = __builtin_amdgcn_mfma_i32_16x16x64_i8(afrag, bfrag, acc[t], 0, 0, 0);
    }
  }
  float qsr[4];
  #pragma unroll
  for (int r = 0; r < 4; ++r) qsr[r] = qs[b * S_ + i0 + g * 4 + r];
  float rm[4] = {0.f, 0.f, 0.f, 0.f};
  #pragma unroll
  for (int t = 0; t < 8; ++t) {
    int j = (w * 8 + t) * 16 + ln;
    bool jv = j < S_;
    float ksv = ks[b * S_ + j];
    #pragma unroll
    for (int r = 0; r < 4; ++r) {
      int ip = i0 + g * 4 + r;
      float av = 0.f;
      if (jv) {
        float simv = __fmul_rn(__fmul_rn((float)acc[t][r], qsr[r]), ksv);
        simv = __fadd_rn(simv, __fmul_rn(rel[t5_bucket(ip, j)], 11.313708498984761f));
        float rr = fmaxf(__fdiv_rn(simv, 500.0f), 0.f);
        av = __fmul_rn(rr, rr);
      }
      rm[r] = fmaxf(rm[r], av);
      acc[t][r] = __float_as_int(av);
    }
  }
  #pragma unroll
  for (int r = 0; r < 4; ++r) atomicMax(&rowmax[g * 4 + r], __float_as_int(rm[r]));
  __syncthreads();
  #pragma unroll
  for (int r = 0; r < 4; ++r) qsr[r] = __int_as_float(rowmax[g * 4 + r]) / 15.0f;
  #pragma unroll
  for (int t = 0; t < 8; ++t) {
    int j = (w * 8 + t) * 16 + ln;
    #pragma unroll
    for (int r = 0; r < 4; ++r) {
      int ip = i0 + g * 4 + r;
      if (ip < S_)
        aq8[((size_t)b * S_ + ip) * 512 + j] =
            (j < S_) ? (signed char)quant15(__int_as_float(acc[t][r]), qsr[r])
                     : (signed char)0;
    }
  }
  if (tid < 16 && i0 + tid < S_)
    as_[b * S_ + i0 + tid] = __int_as_float(rowmax[tid]) / 15.0f;
}

// ---------- kernel 6: quantize v over axis=1 (transposed, padded out) ----------
__global__ __launch_bounds__(256) void k_vq(const float* __restrict__ v,
                                            signed char* __restrict__ vqt,  // [B][640][512]
                                            float* __restrict__ vs) {       // [B][640]
  int d = blockIdx.x * 256 + threadIdx.x;
  int b = blockIdx.y;
  if (d >= HID_) return;
  const float* vp = v + (size_t)b * S_ * HID_ + d;
  float m = 0.f;
  for (int s = 0; s < S_; ++s) m = fmaxf(m, fabsf(vp[(size_t)s * HID_]));
  float vsv = m / 15.0f;
  vs[b * 640 + d] = vsv;
  signed char* o = vqt + ((size_t)b * 640 + d) * 512;
  for (int s = 0; s < S_; ++s) o[s] = (signed char)quant15(vp[(size_t)s * HID_], vsv);
  for (int s = S_; s < 512; ++s) o[s] = 0;
}

// ---------- kernel 7: MFMA i8 PV + gate + /out_s + row-quant ----------
// block 256 (4 waves); block = 16 i-rows x 640 d; wave w owns d-tiles w*10..w*10+9
__global__ __launch_bounds__(256) void k_pv(
    const signed char* __restrict__ aq8,   // [NROW+16][512]
    const float* __restrict__ as_,         // padded
    const signed char* __restrict__ vqt,   // [B][640][512]
    const float* __restrict__ vs,          // [B][640]
    const float* __restrict__ gate,        // [NROW+16][600]
    const float* __restrict__ out_s,       // [600]
    signed char* __restrict__ oq8,         // [NROW][608]
    float* __restrict__ osc) {
  int i0 = blockIdx.x * 16;
  int b = blockIdx.y;
  int tid = threadIdx.x;
  int w = tid >> 6, l = tid & 63, g = l >> 4, ln = l & 15;
  __shared__ __align__(16) signed char a_lds[16 * 528];
  __shared__ int rowmax[16];
  #pragma unroll
  for (int rep = 0; rep < 2; ++rep) {
    int linear = rep * 256 + tid;        // 0..511
    int r = linear >> 5, ww = linear & 31;
    *(v4i*)(a_lds + r * 528 + ww * 16) =
        *(const v4i*)(aq8 + ((size_t)(b * S_ + i0 + r)) * 512 + ww * 16);
  }
  if (tid < 16) rowmax[tid] = 0;
  __syncthreads();
  v4i acc[10];
  v4i zero = {0, 0, 0, 0};
  #pragma unroll
  for (int t = 0; t < 10; ++t) acc[t] = zero;
  for (int kk = 0; kk < 8; ++kk) {
    v4i afrag = *(const v4i*)(a_lds + ln * 528 + kk * 64 + g * 16);
    #pragma unroll
    for (int t = 0; t < 10; ++t) {
      int d0 = (w * 10 + t) * 16;
      v4i bfrag = *(const v4i*)(vqt + ((size_t)b * 640 + d0 + ln) * 512 + kk * 64 + g * 16);
      acc[t] = __builtin_amdgcn_mfma_i32_16x16x64_i8(afrag, bfrag, acc[t], 0, 0, 0);
    }
  }
  float asr[4];
  #pragma unroll
  for (int r = 0; r < 4; ++r) asr[r] = as_[b * S_ + i0 + g * 4 + r];
  float rm[4] = {0.f, 0.f, 0.f, 0.f};
  #pragma unroll
  for (int t = 0; t < 10; ++t) {
    int d = (w * 10 + t) * 16 + ln;
    bool dv = d < HID_;
    float vsv = vs[b * 640 + d];
    float outs = dv ? out_s[d] : 1.0f;
    #pragma unroll
    for (int r = 0; r < 4; ++r) {
      int grow = b * S_ + i0 + g * 4 + r;
      float o = 0.f;
      if (dv) {
        o = __fmul_rn(__fmul_rn((float)acc[t][r], asr[r]), vsv);
        o = __fmul_rn(o, gate[(size_t)grow * HID_ + d]);
        o = __fdiv_rn(o, outs);
      }
      rm[r] = fmaxf(rm[r], fabsf(o));
      acc[t][r] = __float_as_int(o);
    }
  }
  #pragma unroll
  for (int r = 0; r < 4; ++r) atomicMax(&rowmax[g * 4 + r], __float_as_int(rm[r]));
  __syncthreads();
  #pragma unroll
  for (int r = 0; r < 4; ++r) asr[r] = __int_as_float(rowmax[g * 4 + r]) / 15.0f;
  #pragma unroll
  for (int t = 0; t < 10; ++t) {
    int d = (w * 10 + t) * 16 + ln;
    #pragma unroll
    for (int r = 0; r < 4; ++r) {
      int il = i0 + g * 4 + r;
      if (d < HID_ && il < S_)
        oq8[((size_t)b * S_ + il) * 608 + d] =
            (signed char)quant15(__int_as_float(acc[t][r]), asr[r]);
    }
  }
  if (tid < 16 && i0 + tid < S_)
    osc[b * S_ + i0 + tid] = __int_as_float(rowmax[tid]) / 15.0f;
}

// ---------- kernel 8: output GEMM (W^T, 16 rows/block) + residual ----------
__global__ __launch_bounds__(320) void k_final(
    const signed char* __restrict__ oq8,   // [NROW][608]
    const float* __restrict__ osc,
    const float* __restrict__ woT,         // [600][300]
    const float* __restrict__ bo, const float* __restrict__ op,
    const float* __restrict__ x, float* __restrict__ out) {
  int row0 = blockIdx.x * 16;
  int tid = threadIdx.x;
  __shared__ __align__(16) float os2[HID_][16];
  __shared__ float oscv[16];
  for (int idx = tid; idx < 16 * HID_; idx += 320) {
    int r = idx / HID_, cc = idx % HID_;
    os2[cc][r] = (float)oq8[(size_t)(row0 + r) * 608 + cc];
  }
  if (tid < 16) oscv[tid] = osc[row0 + tid];
  __syncthreads();
  if (tid < DIM_) {
    int c = tid;
    float acc[16];
    #pragma unroll
    for (int r = 0; r < 16; ++r) acc[r] = 0.f;
    for (int k = 0; k < HID_; ++k) {
      float w = woT[(size_t)k * DIM_ + c];
      const float4* xp = (const float4*)&os2[k][0];
      float4 a0 = xp[0], a1 = xp[1], a2 = xp[2], a3 = xp[3];
      acc[0] += a0.x * w;  acc[1] += a0.y * w;  acc[2] += a0.z * w;  acc[3] += a0.w * w;
      acc[4] += a1.x * w;  acc[5] += a1.y * w;  acc[6] += a1.z * w;  acc[7] += a1.w * w;
      acc[8] += a2.x * w;  acc[9] += a2.y * w;  acc[10] += a2.z * w; acc[11] += a2.w * w;
      acc[12] += a3.x * w; acc[13] += a3.y * w; acc[14] += a3.z * w; acc[15] += a3.w * w;
    }
    float bc = bo[c], opc = op[c];
    #pragma unroll
    for (int r = 0; r < 16; ++r) {
      int grow = row0 + r;
      float t = __fmul_rn(oscv[r], opc);
      out[(size_t)grow * DIM_ + c] =
          __fmul_rn(acc[r] + bc, t) + x[(size_t)grow * DIM_ + c];
    }
  }
}

// ---------- launch ----------
extern "C" void kernel_launch(void* const* d_in, const int* in_sizes, int n_in,
                              void* d_out, int out_size, void* d_ws, size_t ws_size,
                              hipStream_t stream) {
  const float* x        = (const float*)d_in[0];
  const float* ng       = (const float*)d_in[1];
  const float* nbt      = (const float*)d_in[2];
  const float* Wh       = (const float*)d_in[3];
  const float* bh       = (const float*)d_in[4];
  const float* Wqk      = (const float*)d_in[5];
  const float* bqk      = (const float*)d_in[6];
  const float* osg      = (const float*)d_in[7];
  const float* osb      = (const float*)d_in[8];
  const float* Wo       = (const float*)d_in[9];
  const float* bo       = (const float*)d_in[10];
  const float* rel      = (const float*)d_in[11];
  const float* qk_s     = (const float*)d_in[12];
  const float* hidden_s = (const float*)d_in[13];
  const float* out_s    = (const float*)d_in[14];
  const float* hp       = (const float*)d_in[15];
  const float* qkp      = (const float*)d_in[16];
  const float* op       = (const float*)d_in[17];
  float* out = (float*)d_out;

  char* ws = (char*)d_ws;
  size_t off = 0;
  auto alloc = [&](size_t bytes) {
    void* p = ws + off;
    off += (bytes + 255) & ~(size_t)255;
    return p;
  };
  float*       normed = (float*)      alloc((size_t)NROW * DIM_ * 4);
  signed char* xq8    = (signed char*)alloc((size_t)NROW * DIM_);
  signed char* xh8    = (signed char*)alloc((size_t)NROW * DIM_);
  float*       sq     = (float*)      alloc((size_t)(NROW + 16) * 4);
  float*       sh     = (float*)      alloc((size_t)(NROW + 16) * 4);
  float*       v      = (float*)      alloc((size_t)NROW * HID_ * 4);
  float*       gate   = (float*)      alloc((size_t)(NROW + 16) * HID_ * 4);
  signed char* qq8    = (signed char*)alloc((size_t)(NROW + 16) * QK_);
  signed char* kq8    = (signed char*)alloc((size_t)(NROW + 16) * QK_);
  float*       qs     = (float*)      alloc((size_t)(NROW + 16) * 4);
  float*       ks     = (float*)      alloc((size_t)(NROW + 16) * 4);
  signed char* aq8    = (signed char*)alloc((size_t)(NROW + 16) * 512);
  float*       as_    = (float*)      alloc((size_t)(NROW + 16) * 4);
  signed char* vqt    = (signed char*)alloc((size_t)B_ * 640 * 512);
  float*       vs     = (float*)      alloc((size_t)B_ * 640 * 4);
  signed char* oq8    = (signed char*)alloc((size_t)NROW * 608);
  float*       osc    = (float*)      alloc((size_t)NROW * 4);
  float*       whT    = (float*)      alloc((size_t)DIM_ * 2 * HID_ * 4);
  float*       wqkT   = (float*)      alloc((size_t)DIM_ * QK_ * 4);
  float*       woT    = (float*)      alloc((size_t)HID_ * DIM_ * 4);

  k_transpose<<<(2 * HID_ * DIM_ + 255) / 256, 256, 0, stream>>>(Wh, whT, 2 * HID_, DIM_);
  k_transpose<<<(QK_ * DIM_ + 255) / 256, 256, 0, stream>>>(Wqk, wqkT, QK_, DIM_);
  k_transpose<<<(DIM_ * HID_ + 255) / 256, 256, 0, stream>>>(Wo, woT, DIM_, HID_);

  k_ln<<<NROW, 256, 0, stream>>>(x, ng, nbt, normed);
  k_shiftquant<<<NROW, 256, 0, stream>>>(normed, qk_s, hidden_s, xq8, xh8, sq, sh);
  k_hidden<<<(NROW + HR - 1) / HR, 256, 0, stream>>>(xh8, sh, whT, bh, hp, v, gate);
  k_qk<<<NROW / 4, 128, 0, stream>>>(xq8, sq, wqkT, bqk, qkp, osg, osb, qq8, kq8, qs, ks);
  k_sim<<<dim3(32, B_), 256, 0, stream>>>(qq8, kq8, qs, ks, rel, aq8, as_);
  k_vq<<<dim3(3, B_), 256, 0, stream>>>(v, vqt, vs);
  k_pv<<<dim3(32, B_), 256, 0, stream>>>(aq8, as_, vqt, vs, gate, out_s, oq8, osc);
  k_final<<<NROW / 16, 320, 0, stream>>>(oq8, osc, woT, bo, op, x, out);
}

// Round 3
// 364.545 us; speedup vs baseline: 3.0403x; 1.5538x over previous
//
#include <hip/hip_runtime.h>
#include <math.h>

#define B_   20
#define S_   500
#define DIM_ 300
#define QK_  128
#define HID_ 600
#define NROW (B_ * S_)   // 10000

typedef int   v4i    __attribute__((ext_vector_type(4)));
typedef short bf16x8 __attribute__((ext_vector_type(8)));
typedef short short4v __attribute__((ext_vector_type(4)));
typedef float f32x4  __attribute__((ext_vector_type(4)));

// ---- bf16 helpers (RNE, no NaN handling needed for our ranges) ----
__device__ __forceinline__ unsigned short f32_to_bf16(float f) {
  unsigned int u = __float_as_uint(f);
  unsigned int r = (u + 0x7FFFu + ((u >> 16) & 1u)) >> 16;
  return (unsigned short)r;
}
__device__ __forceinline__ float bf16_to_f32(unsigned short s) {
  return __uint_as_float(((unsigned int)s) << 16);
}

// T5 bucket: exact integer thresholds {12,16,23,32,46,64,91}; >=91 -> 15.
__device__ __forceinline__ int t5_bucket(int i, int j) {
  int d = i - j;
  int ret = (d < 0) ? 16 : 0;
  int n = d < 0 ? -d : d;
  int v;
  if (n < 8)       v = n;
  else if (n < 12) v = 8;
  else if (n < 16) v = 9;
  else if (n < 23) v = 10;
  else if (n < 32) v = 11;
  else if (n < 46) v = 12;
  else if (n < 64) v = 13;
  else if (n < 91) v = 14;
  else             v = 15;
  return ret + v;
}

__device__ __forceinline__ float quant15(float y, float s) {
  return truncf(fminf(fmaxf(__fdiv_rn(y, s), -15.f), 15.f));
}

// ---------- transpose (Wqk only): src[R][C] -> dst[C][R] ----------
__global__ __launch_bounds__(256) void k_transpose(const float* __restrict__ src,
                                                   float* __restrict__ dst,
                                                   int R, int C) {
  int idx = blockIdx.x * 256 + threadIdx.x;
  if (idx < R * C) {
    int r = idx / C, c = idx % C;
    dst[(size_t)c * R + r] = src[idx];
  }
}

// ---------- weight split: src[R][C] f32 -> hi/lo bf16 [RP][KP] ----------
__global__ __launch_bounds__(256) void k_wsplit(const float* __restrict__ src,
                                                unsigned short* __restrict__ hi,
                                                unsigned short* __restrict__ lo,
                                                int R, int C, int KP, int total) {
  int idx = blockIdx.x * 256 + threadIdx.x;
  if (idx >= total) return;
  int r = idx / KP, k = idx % KP;
  float val = (r < R && k < C) ? src[(size_t)r * C + k] : 0.f;
  unsigned short h = f32_to_bf16(val);
  float rem = val - bf16_to_f32(h);
  hi[idx] = h;
  lo[idx] = f32_to_bf16(rem);
}

// ---------- kernel 1: layernorm ----------
__global__ __launch_bounds__(256) void k_ln(const float* __restrict__ x,
                                            const float* __restrict__ g,
                                            const float* __restrict__ b,
                                            float* __restrict__ normed) {
  int row = blockIdx.x;
  const float* xr = x + (size_t)row * DIM_;
  __shared__ float red[256];
  int tid = threadIdx.x;
  float s = 0.f;
  for (int c = tid; c < DIM_; c += 256) s += xr[c];
  red[tid] = s; __syncthreads();
  for (int off = 128; off > 0; off >>= 1) {
    if (tid < off) red[tid] += red[tid + off];
    __syncthreads();
  }
  float mu = red[0] / (float)DIM_;
  __syncthreads();
  float s2 = 0.f;
  for (int c = tid; c < DIM_; c += 256) { float d = xr[c] - mu; s2 += d * d; }
  red[tid] = s2; __syncthreads();
  for (int off = 128; off > 0; off >>= 1) {
    if (tid < off) red[tid] += red[tid + off];
    __syncthreads();
  }
  float var = red[0] / (float)DIM_;
  float denom = sqrtf(var + 1e-5f);
  for (int c = tid; c < DIM_; c += 256)
    normed[(size_t)row * DIM_ + c] = __fdiv_rn(xr[c] - mu, denom) * g[c] + b[c];
}

// ---------- kernel 2: token shift + dual row-quant ----------
__global__ __launch_bounds__(256) void k_shiftquant(
    const float* __restrict__ normed,
    const float* __restrict__ qk_s, const float* __restrict__ hidden_s,
    signed char* __restrict__ xq8, signed char* __restrict__ xh8,
    float* __restrict__ sq, float* __restrict__ sh) {
  int row = blockIdx.x;
  int s_idx = row % S_;
  int tid = threadIdx.x;
  __shared__ float redq[256], redh[256];
  float yq[2], yh[2];
  float mq = 0.f, mh = 0.f;
  #pragma unroll
  for (int it = 0; it < 2; ++it) {
    int c = tid + it * 256;
    if (c < DIM_) {
      float src;
      if (c < DIM_ / 2) src = (s_idx > 0) ? normed[(size_t)(row - 1) * DIM_ + c] : 0.f;
      else              src = normed[(size_t)row * DIM_ + c];
      yq[it] = __fdiv_rn(src, qk_s[c]);
      yh[it] = __fdiv_rn(src, hidden_s[c]);
      mq = fmaxf(mq, fabsf(yq[it]));
      mh = fmaxf(mh, fabsf(yh[it]));
    }
  }
  redq[tid] = mq; redh[tid] = mh; __syncthreads();
  for (int off = 128; off > 0; off >>= 1) {
    if (tid < off) {
      redq[tid] = fmaxf(redq[tid], redq[tid + off]);
      redh[tid] = fmaxf(redh[tid], redh[tid + off]);
    }
    __syncthreads();
  }
  float sqv = redq[0] / 15.0f, shv = redh[0] / 15.0f;
  if (tid == 0) { sq[row] = sqv; sh[row] = shv; }
  #pragma unroll
  for (int it = 0; it < 2; ++it) {
    int c = tid + it * 256;
    if (c < DIM_) {
      xq8[(size_t)row * DIM_ + c] = (signed char)quant15(yq[it], sqv);
      xh8[(size_t)row * DIM_ + c] = (signed char)quant15(yh[it], shv);
    }
  }
}

// ---------- kernel 3: hidden GEMM via bf16-split MFMA ----------
// 32 rows/block, 4 waves; wave w = col-quarter (19 tiles of 16), both slabs.
#define KP_H  320
#define LDA_H 328
__global__ __launch_bounds__(256) void k_hidden(
    const signed char* __restrict__ xh8, const float* __restrict__ sh,
    const unsigned short* __restrict__ whHi, const unsigned short* __restrict__ whLo,
    const float* __restrict__ bh, const float* __restrict__ hp,
    float* __restrict__ v, float* __restrict__ gate) {
  int i0 = blockIdx.x * 32;
  int tid = threadIdx.x;
  int w = tid >> 6, l = tid & 63, g = l >> 4, ln = l & 15;
  __shared__ unsigned short a_lds[32 * LDA_H];
  // stage A: 32 rows x 320 k (int8 -> bf16 exact), u32-chunked
  for (int idx = tid; idx < 32 * 80; idx += 256) {
    int r = idx / 80, kc = idx % 80;
    int grow = i0 + r; if (grow >= NROW) grow = NROW - 1;
    unsigned int u = 0;
    if (kc < 75) u = *(const unsigned int*)(xh8 + (size_t)grow * DIM_ + kc * 4);
    short4v st;
    st.x = (short)f32_to_bf16((float)(signed char)(u       & 0xff));
    st.y = (short)f32_to_bf16((float)(signed char)((u >> 8) & 0xff));
    st.z = (short)f32_to_bf16((float)(signed char)((u >> 16) & 0xff));
    st.w = (short)f32_to_bf16((float)(signed char)((u >> 24) & 0xff));
    *(short4v*)&a_lds[r * LDA_H + kc * 4] = st;
  }
  __syncthreads();
  bf16x8 af0[10], af1[10];
  #pragma unroll
  for (int kk = 0; kk < 10; ++kk) {
    af0[kk] = *(const bf16x8*)&a_lds[ln * LDA_H + kk * 32 + g * 8];
    af1[kk] = *(const bf16x8*)&a_lds[(16 + ln) * LDA_H + kk * 32 + g * 8];
  }
  float sh_r[2][4];
  #pragma unroll
  for (int sl = 0; sl < 2; ++sl)
    #pragma unroll
    for (int r = 0; r < 4; ++r) {
      int grow = i0 + sl * 16 + g * 4 + r;
      sh_r[sl][r] = sh[grow < NROW ? grow : NROW - 1];
    }
  for (int t = 0; t < 19; ++t) {
    int j0 = (w * 19 + t) * 16;
    const unsigned short* bhp = whHi + (size_t)(j0 + ln) * KP_H + g * 8;
    const unsigned short* blp = whLo + (size_t)(j0 + ln) * KP_H + g * 8;
    f32x4 acc0 = {0.f, 0.f, 0.f, 0.f}, acc1 = {0.f, 0.f, 0.f, 0.f};
    #pragma unroll
    for (int kk = 0; kk < 10; ++kk) {
      bf16x8 bhv = *(const bf16x8*)(bhp + kk * 32);
      bf16x8 blv = *(const bf16x8*)(blp + kk * 32);
      acc0 = __builtin_amdgcn_mfma_f32_16x16x32_bf16(af0[kk], bhv, acc0, 0, 0, 0);
      acc0 = __builtin_amdgcn_mfma_f32_16x16x32_bf16(af0[kk], blv, acc0, 0, 0, 0);
      acc1 = __builtin_amdgcn_mfma_f32_16x16x32_bf16(af1[kk], bhv, acc1, 0, 0, 0);
      acc1 = __builtin_amdgcn_mfma_f32_16x16x32_bf16(af1[kk], blv, acc1, 0, 0, 0);
    }
    int col = j0 + ln;
    if (col < 2 * HID_) {
      float bc = bh[col], hpc = hp[col];
      #pragma unroll
      for (int sl = 0; sl < 2; ++sl) {
        #pragma unroll
        for (int r = 0; r < 4; ++r) {
          int grow = i0 + sl * 16 + g * 4 + r;
          if (grow < NROW) {
            float z = (sl ? acc1[r] : acc0[r]) + bc;
            float sig = 1.0f / (1.0f + __expf(-z));
            float val = __fmul_rn(z * sig, __fmul_rn(sh_r[sl][r], hpc));
            if (col < HID_) v[(size_t)grow * HID_ + col] = val;
            else            gate[(size_t)grow * HID_ + (col - HID_)] = val;
          }
        }
      }
    }
  }
}

// ---------- kernel 4: qk GEMM (W^T, 4 rows/block) + silu + rotary + quant ----------
__global__ __launch_bounds__(128) void k_qk(
    const signed char* __restrict__ xq8, const float* __restrict__ sq,
    const float* __restrict__ wqkT,   // [300][128]
    const float* __restrict__ bqk,
    const float* __restrict__ qkp, const float* __restrict__ osg,
    const float* __restrict__ osb,
    signed char* __restrict__ qq8, signed char* __restrict__ kq8,
    float* __restrict__ qs, float* __restrict__ ks) {
  int row0 = blockIdx.x * 4;
  int c = threadIdx.x;   // 0..127
  __shared__ float xs[4][DIM_];
  __shared__ float qbuf[4][QK_], kbuf[4][QK_];
  __shared__ float redq[4][QK_], redk[4][QK_];
  for (int idx = c; idx < 4 * DIM_; idx += 128) {
    int r = idx / DIM_, cc = idx % DIM_;
    xs[r][cc] = (float)xq8[(size_t)(row0 + r) * DIM_ + cc];
  }
  __syncthreads();
  float acc[4] = {0.f, 0.f, 0.f, 0.f};
  for (int k = 0; k < DIM_; ++k) {
    float w = wqkT[k * QK_ + c];
    #pragma unroll
    for (int r = 0; r < 4; ++r) acc[r] += xs[r][k] * w;
  }
  float bc = bqk[c], qkpc = qkp[c];
  float g0 = osg[c], g1 = osg[QK_ + c], b0 = osb[c], b1 = osb[QK_ + c];
  float qv[4], kv[4];
  #pragma unroll
  for (int r = 0; r < 4; ++r) {
    float z = acc[r] + bc;
    float sig = 1.0f / (1.0f + expf(-z));
    float qkv = __fmul_rn(z * sig, __fmul_rn(sq[row0 + r], qkpc));
    qv[r] = __fadd_rn(__fmul_rn(qkv, g0), b0);
    kv[r] = __fadd_rn(__fmul_rn(qkv, g1), b1);
    qbuf[r][c] = qv[r]; kbuf[r][c] = kv[r];
  }
  __syncthreads();
  if (c < 32) {
    double e = (double)(c & ~1) / 32.0;
    float inv = (float)(1.0 / pow(10000.0, e));
    #pragma unroll
    for (int r = 0; r < 4; ++r) {
      int pos = (row0 + r) % S_;
      float fr = __fmul_rn((float)pos, inv);
      float cs = cosf(fr), sn = sinf(fr);
      float rq = ((c & 1) == 0) ? -qbuf[r][c + 1] : qbuf[r][c - 1];
      float rk = ((c & 1) == 0) ? -kbuf[r][c + 1] : kbuf[r][c - 1];
      qv[r] = __fadd_rn(__fmul_rn(qv[r], cs), __fmul_rn(rq, sn));
      kv[r] = __fadd_rn(__fmul_rn(kv[r], cs), __fmul_rn(rk, sn));
    }
  }
  #pragma unroll
  for (int r = 0; r < 4; ++r) { redq[r][c] = fabsf(qv[r]); redk[r][c] = fabsf(kv[r]); }
  __syncthreads();
  for (int off = 64; off > 0; off >>= 1) {
    if (c < off) {
      #pragma unroll
      for (int r = 0; r < 4; ++r) {
        redq[r][c] = fmaxf(redq[r][c], redq[r][c + off]);
        redk[r][c] = fmaxf(redk[r][c], redk[r][c + off]);
      }
    }
    __syncthreads();
  }
  #pragma unroll
  for (int r = 0; r < 4; ++r) {
    float qsv = redq[r][0] / 15.0f, ksv = redk[r][0] / 15.0f;
    if (c == 0) { qs[row0 + r] = qsv; ks[row0 + r] = ksv; }
    qq8[(size_t)(row0 + r) * QK_ + c] = (signed char)quant15(qv[r], qsv);
    kq8[(size_t)(row0 + r) * QK_ + c] = (signed char)quant15(kv[r], ksv);
  }
}

// ---------- kernel 5: MFMA i8 QK^T + T5 bias + relu^2 + row-quant ----------
__global__ __launch_bounds__(256) void k_sim(
    const signed char* __restrict__ qq8, const signed char* __restrict__ kq8,
    const float* __restrict__ qs, const float* __restrict__ ks,
    const float* __restrict__ rel_emb,
    signed char* __restrict__ aq8, float* __restrict__ as_) {
  int i0 = blockIdx.x * 16;
  int b = blockIdx.y;
  int tid = threadIdx.x;
  int w = tid >> 6, l = tid & 63, g = l >> 4, ln = l & 15;
  __shared__ __align__(16) signed char a_lds[16 * 144];
  __shared__ float rel[32];
  __shared__ int rowmax[16];
  if (tid < 128) {
    int r = tid >> 3, ww = tid & 7;
    *(v4i*)(a_lds + r * 144 + ww * 16) =
        *(const v4i*)(qq8 + ((size_t)(b * S_ + i0 + r)) * QK_ + ww * 16);
  }
  if (tid < 32) rel[tid] = rel_emb[tid];
  if (tid < 16) rowmax[tid] = 0;
  __syncthreads();
  v4i acc[8];
  v4i zero = {0, 0, 0, 0};
  #pragma unroll
  for (int t = 0; t < 8; ++t) acc[t] = zero;
  #pragma unroll
  for (int kk = 0; kk < 2; ++kk) {
    v4i afrag = *(const v4i*)(a_lds + ln * 144 + kk * 64 + g * 16);
    #pragma unroll
    for (int t = 0; t < 8; ++t) {
      int j0 = (w * 8 + t) * 16;
      v4i bfrag = *(const v4i*)(kq8 + ((size_t)(b * S_ + j0 + ln)) * QK_ + kk * 64 + g * 16);
      acc[t] = __builtin_amdgcn_mfma_i32_16x16x64_i8(afrag, bfrag, acc[t], 0, 0, 0);
    }
  }
  float qsr[4];
  #pragma unroll
  for (int r = 0; r < 4; ++r) qsr[r] = qs[b * S_ + i0 + g * 4 + r];
  float rm[4] = {0.f, 0.f, 0.f, 0.f};
  #pragma unroll
  for (int t = 0; t < 8; ++t) {
    int j = (w * 8 + t) * 16 + ln;
    bool jv = j < S_;
    float ksv = ks[b * S_ + j];
    #pragma unroll
    for (int r = 0; r < 4; ++r) {
      int ip = i0 + g * 4 + r;
      float av = 0.f;
      if (jv) {
        float simv = __fmul_rn(__fmul_rn((float)acc[t][r], qsr[r]), ksv);
        simv = __fadd_rn(simv, __fmul_rn(rel[t5_bucket(ip, j)], 11.313708498984761f));
        float rr = fmaxf(__fdiv_rn(simv, 500.0f), 0.f);
        av = __fmul_rn(rr, rr);
      }
      rm[r] = fmaxf(rm[r], av);
      acc[t][r] = __float_as_int(av);
    }
  }
  #pragma unroll
  for (int r = 0; r < 4; ++r) atomicMax(&rowmax[g * 4 + r], __float_as_int(rm[r]));
  __syncthreads();
  #pragma unroll
  for (int r = 0; r < 4; ++r) qsr[r] = __int_as_float(rowmax[g * 4 + r]) / 15.0f;
  #pragma unroll
  for (int t = 0; t < 8; ++t) {
    int j = (w * 8 + t) * 16 + ln;
    #pragma unroll
    for (int r = 0; r < 4; ++r) {
      int ip = i0 + g * 4 + r;
      if (ip < S_)
        aq8[((size_t)b * S_ + ip) * 512 + j] =
            (j < S_) ? (signed char)quant15(__int_as_float(acc[t][r]), qsr[r])
                     : (signed char)0;
    }
  }
  if (tid < 16 && i0 + tid < S_)
    as_[b * S_ + i0 + tid] = __int_as_float(rowmax[tid]) / 15.0f;
}

// ---------- kernel 6a: per-(b,d) max over s (coalesced) ----------
__global__ __launch_bounds__(256) void k_vmax(const float* __restrict__ v,
                                              int* __restrict__ vsmax) {
  int b = blockIdx.y;
  int s0 = blockIdx.x * 50;
  int tid = threadIdx.x;
  float m[3] = {0.f, 0.f, 0.f};
  for (int s = s0; s < s0 + 50; ++s) {
    const float* vp = v + ((size_t)b * S_ + s) * HID_;
    #pragma unroll
    for (int it = 0; it < 3; ++it) {
      int d = tid + it * 256;
      if (d < HID_) m[it] = fmaxf(m[it], fabsf(vp[d]));
    }
  }
  #pragma unroll
  for (int it = 0; it < 3; ++it) {
    int d = tid + it * 256;
    if (d < HID_) atomicMax(&vsmax[b * 640 + d], __float_as_int(m[it]));
  }
}

// ---------- kernel 6b: quantize+transpose v (64x64 LDS tiles) ----------
__global__ __launch_bounds__(256) void k_vq2(const float* __restrict__ v,
                                             const int* __restrict__ vsmax,
                                             signed char* __restrict__ vqt,  // [B][640][512]
                                             float* __restrict__ vs) {       // [B][640]
  int b = blockIdx.z;
  int s0 = blockIdx.x * 64;   // 8 tiles -> 512
  int d0 = blockIdx.y * 64;   // 10 tiles -> 640
  __shared__ float tile[64][65];
  int tid = threadIdx.x;
  int dj = tid & 63, si4 = tid >> 6;
  #pragma unroll
  for (int it = 0; it < 16; ++it) {
    int s = s0 + it * 4 + si4;
    int d = d0 + dj;
    float val = 0.f;
    if (s < S_ && d < HID_) val = v[((size_t)b * S_ + s) * HID_ + d];
    tile[it * 4 + si4][dj] = val;
  }
  if (blockIdx.x == 0 && tid < 64 && d0 + tid < HID_)
    vs[b * 640 + d0 + tid] = __int_as_float(vsmax[b * 640 + d0 + tid]) / 15.0f;
  __syncthreads();
  int dd = tid >> 2, seg = tid & 3;
  int d = d0 + dd;
  if (d < HID_) {
    float vsv = __int_as_float(vsmax[b * 640 + d]) / 15.0f;
    v4i pack;
    signed char* pc = (signed char*)&pack;
    #pragma unroll
    for (int e = 0; e < 16; ++e)
      pc[e] = (signed char)quant15(tile[seg * 16 + e][dd], vsv);
    *(v4i*)(vqt + ((size_t)b * 640 + d) * 512 + s0 + seg * 16) = pack;
  }
}

// ---------- kernel 7: MFMA i8 PV + gate + /out_s + row-quant ----------
__global__ __launch_bounds__(256) void k_pv(
    const signed char* __restrict__ aq8, const float* __restrict__ as_,
    const signed char* __restrict__ vqt, const float* __restrict__ vs,
    const float* __restrict__ gate, const float* __restrict__ out_s,
    signed char* __restrict__ oq8, float* __restrict__ osc) {
  int i0 = blockIdx.x * 16;
  int b = blockIdx.y;
  int tid = threadIdx.x;
  int w = tid >> 6, l = tid & 63, g = l >> 4, ln = l & 15;
  __shared__ __align__(16) signed char a_lds[16 * 528];
  __shared__ int rowmax[16];
  #pragma unroll
  for (int rep = 0; rep < 2; ++rep) {
    int linear = rep * 256 + tid;
    int r = linear >> 5, ww = linear & 31;
    *(v4i*)(a_lds + r * 528 + ww * 16) =
        *(const v4i*)(aq8 + ((size_t)(b * S_ + i0 + r)) * 512 + ww * 16);
  }
  if (tid < 16) rowmax[tid] = 0;
  __syncthreads();
  v4i acc[10];
  v4i zero = {0, 0, 0, 0};
  #pragma unroll
  for (int t = 0; t < 10; ++t) acc[t] = zero;
  for (int kk = 0; kk < 8; ++kk) {
    v4i afrag = *(const v4i*)(a_lds + ln * 528 + kk * 64 + g * 16);
    #pragma unroll
    for (int t = 0; t < 10; ++t) {
      int d0 = (w * 10 + t) * 16;
      v4i bfrag = *(const v4i*)(vqt + ((size_t)b * 640 + d0 + ln) * 512 + kk * 64 + g * 16);
      acc[t] = __builtin_amdgcn_mfma_i32_16x16x64_i8(afrag, bfrag, acc[t], 0, 0, 0);
    }
  }
  float asr[4];
  #pragma unroll
  for (int r = 0; r < 4; ++r) asr[r] = as_[b * S_ + i0 + g * 4 + r];
  float rm[4] = {0.f, 0.f, 0.f, 0.f};
  #pragma unroll
  for (int t = 0; t < 10; ++t) {
    int d = (w * 10 + t) * 16 + ln;
    bool dv = d < HID_;
    float vsv = vs[b * 640 + d];
    float outs = dv ? out_s[d] : 1.0f;
    #pragma unroll
    for (int r = 0; r < 4; ++r) {
      int grow = b * S_ + i0 + g * 4 + r;
      float o = 0.f;
      if (dv) {
        o = __fmul_rn(__fmul_rn((float)acc[t][r], asr[r]), vsv);
        o = __fmul_rn(o, gate[(size_t)grow * HID_ + d]);
        o = __fdiv_rn(o, outs);
      }
      rm[r] = fmaxf(rm[r], fabsf(o));
      acc[t][r] = __float_as_int(o);
    }
  }
  #pragma unroll
  for (int r = 0; r < 4; ++r) atomicMax(&rowmax[g * 4 + r], __float_as_int(rm[r]));
  __syncthreads();
  #pragma unroll
  for (int r = 0; r < 4; ++r) asr[r] = __int_as_float(rowmax[g * 4 + r]) / 15.0f;
  #pragma unroll
  for (int t = 0; t < 10; ++t) {
    int d = (w * 10 + t) * 16 + ln;
    #pragma unroll
    for (int r = 0; r < 4; ++r) {
      int il = i0 + g * 4 + r;
      if (d < HID_ && il < S_)
        oq8[((size_t)b * S_ + il) * 608 + d] =
            (signed char)quant15(__int_as_float(acc[t][r]), asr[r]);
    }
  }
  if (tid < 16 && i0 + tid < S_)
    osc[b * S_ + i0 + tid] = __int_as_float(rowmax[tid]) / 15.0f;
}

// ---------- kernel 8: output GEMM via bf16-split MFMA + residual ----------
// 32 rows/block, 4 waves; 19 col-tiles, wave w takes tiles w, w+4, ...
#define KP_F  608
#define LDA_F 616
__global__ __launch_bounds__(256) void k_final(
    const signed char* __restrict__ oq8,   // [NROW][608]
    const float* __restrict__ osc,
    const unsigned short* __restrict__ woHi, const unsigned short* __restrict__ woLo,
    const float* __restrict__ bo, const float* __restrict__ op,
    const float* __restrict__ x, float* __restrict__ out) {
  int i0 = blockIdx.x * 32;
  int tid = threadIdx.x;
  int w = tid >> 6, l = tid & 63, g = l >> 4, ln = l & 15;
  __shared__ unsigned short a_lds[32 * LDA_F];
  // stage A: 32 rows x 608 k (int8 -> bf16), u32-chunked (608/4 = 152)
  for (int idx = tid; idx < 32 * 152; idx += 256) {
    int r = idx / 152, kc = idx % 152;
    int grow = i0 + r; if (grow >= NROW) grow = NROW - 1;
    unsigned int u = *(const unsigned int*)(oq8 + (size_t)grow * 608 + kc * 4);
    short4v st;
    st.x = (short)f32_to_bf16((float)(signed char)(u       & 0xff));
    st.y = (short)f32_to_bf16((float)(signed char)((u >> 8) & 0xff));
    st.z = (short)f32_to_bf16((float)(signed char)((u >> 16) & 0xff));
    st.w = (short)f32_to_bf16((float)(signed char)((u >> 24) & 0xff));
    *(short4v*)&a_lds[r * LDA_F + kc * 4] = st;
  }
  __syncthreads();
  float osc_r[2][4];
  #pragma unroll
  for (int sl = 0; sl < 2; ++sl)
    #pragma unroll
    for (int r = 0; r < 4; ++r) {
      int grow = i0 + sl * 16 + g * 4 + r;
      osc_r[sl][r] = osc[grow < NROW ? grow : NROW - 1];
    }
  for (int t = w; t < 19; t += 4) {
    int j0 = t * 16;
    const unsigned short* bhp = woHi + (size_t)(j0 + ln) * KP_F + g * 8;
    const unsigned short* blp = woLo + (size_t)(j0 + ln) * KP_F + g * 8;
    f32x4 acc0 = {0.f, 0.f, 0.f, 0.f}, acc1 = {0.f, 0.f, 0.f, 0.f};
    for (int kk = 0; kk < 19; ++kk) {
      bf16x8 a0 = *(const bf16x8*)&a_lds[ln * LDA_F + kk * 32 + g * 8];
      bf16x8 a1 = *(const bf16x8*)&a_lds[(16 + ln) * LDA_F + kk * 32 + g * 8];
      bf16x8 bhv = *(const bf16x8*)(bhp + kk * 32);
      bf16x8 blv = *(const bf16x8*)(blp + kk * 32);
      acc0 = __builtin_amdgcn_mfma_f32_16x16x32_bf16(a0, bhv, acc0, 0, 0, 0);
      acc0 = __builtin_amdgcn_mfma_f32_16x16x32_bf16(a0, blv, acc0, 0, 0, 0);
      acc1 = __builtin_amdgcn_mfma_f32_16x16x32_bf16(a1, bhv, acc1, 0, 0, 0);
      acc1 = __builtin_amdgcn_mfma_f32_16x16x32_bf16(a1, blv, acc1, 0, 0, 0);
    }
    int col = j0 + ln;
    if (col < DIM_) {
      float bc = bo[col], opc = op[col];
      #pragma unroll
      for (int sl = 0; sl < 2; ++sl) {
        #pragma unroll
        for (int r = 0; r < 4; ++r) {
          int grow = i0 + sl * 16 + g * 4 + r;
          if (grow < NROW) {
            float tval = __fmul_rn(osc_r[sl][r], opc);
            float res = __fmul_rn((sl ? acc1[r] : acc0[r]) + bc, tval);
            out[(size_t)grow * DIM_ + col] = res + x[(size_t)grow * DIM_ + col];
          }
        }
      }
    }
  }
}

// ---------- launch ----------
extern "C" void kernel_launch(void* const* d_in, const int* in_sizes, int n_in,
                              void* d_out, int out_size, void* d_ws, size_t ws_size,
                              hipStream_t stream) {
  const float* x        = (const float*)d_in[0];
  const float* ng       = (const float*)d_in[1];
  const float* nbt      = (const float*)d_in[2];
  const float* Wh       = (const float*)d_in[3];
  const float* bh       = (const float*)d_in[4];
  const float* Wqk      = (const float*)d_in[5];
  const float* bqk      = (const float*)d_in[6];
  const float* osg      = (const float*)d_in[7];
  const float* osb      = (const float*)d_in[8];
  const float* Wo       = (const float*)d_in[9];
  const float* bo       = (const float*)d_in[10];
  const float* rel      = (const float*)d_in[11];
  const float* qk_s     = (const float*)d_in[12];
  const float* hidden_s = (const float*)d_in[13];
  const float* out_s    = (const float*)d_in[14];
  const float* hp       = (const float*)d_in[15];
  const float* qkp      = (const float*)d_in[16];
  const float* op       = (const float*)d_in[17];
  float* out = (float*)d_out;

  char* ws = (char*)d_ws;
  size_t off = 0;
  auto alloc = [&](size_t bytes) {
    void* p = ws + off;
    off += (bytes + 255) & ~(size_t)255;
    return p;
  };
  float*       normed = (float*)      alloc((size_t)NROW * DIM_ * 4);
  signed char* xq8    = (signed char*)alloc((size_t)NROW * DIM_);
  signed char* xh8    = (signed char*)alloc((size_t)NROW * DIM_);
  float*       sq     = (float*)      alloc((size_t)(NROW + 16) * 4);
  float*       sh     = (float*)      alloc((size_t)(NROW + 16) * 4);
  float*       v      = (float*)      alloc((size_t)NROW * HID_ * 4);
  float*       gate   = (float*)      alloc((size_t)(NROW + 16) * HID_ * 4);
  signed char* qq8    = (signed char*)alloc((size_t)(NROW + 16) * QK_);
  signed char* kq8    = (signed char*)alloc((size_t)(NROW + 16) * QK_);
  float*       qs     = (float*)      alloc((size_t)(NROW + 16) * 4);
  float*       ks     = (float*)      alloc((size_t)(NROW + 16) * 4);
  signed char* aq8    = (signed char*)alloc((size_t)(NROW + 16) * 512);
  float*       as_    = (float*)      alloc((size_t)(NROW + 16) * 4);
  signed char* vqt    = (signed char*)alloc((size_t)B_ * 640 * 512);
  float*       vs     = (float*)      alloc((size_t)B_ * 640 * 4);
  int*         vsmax  = (int*)        alloc((size_t)B_ * 640 * 4);
  signed char* oq8    = (signed char*)alloc((size_t)NROW * 608);
  float*       osc    = (float*)      alloc((size_t)NROW * 4);
  unsigned short* whHi = (unsigned short*)alloc((size_t)1216 * KP_H * 2);
  unsigned short* whLo = (unsigned short*)alloc((size_t)1216 * KP_H * 2);
  unsigned short* woHi = (unsigned short*)alloc((size_t)304 * KP_F * 2);
  unsigned short* woLo = (unsigned short*)alloc((size_t)304 * KP_F * 2);
  float*       wqkT   = (float*)      alloc((size_t)DIM_ * QK_ * 4);

  hipMemsetAsync(vsmax, 0, (size_t)B_ * 640 * 4, stream);

  k_wsplit<<<(1216 * KP_H + 255) / 256, 256, 0, stream>>>(Wh, whHi, whLo,
                                                          2 * HID_, DIM_, KP_H, 1216 * KP_H);
  k_wsplit<<<(304 * KP_F + 255) / 256, 256, 0, stream>>>(Wo, woHi, woLo,
                                                         DIM_, HID_, KP_F, 304 * KP_F);
  k_transpose<<<(QK_ * DIM_ + 255) / 256, 256, 0, stream>>>(Wqk, wqkT, QK_, DIM_);

  k_ln<<<NROW, 256, 0, stream>>>(x, ng, nbt, normed);
  k_shiftquant<<<NROW, 256, 0, stream>>>(normed, qk_s, hidden_s, xq8, xh8, sq, sh);
  k_hidden<<<(NROW + 31) / 32, 256, 0, stream>>>(xh8, sh, whHi, whLo, bh, hp, v, gate);
  k_qk<<<NROW / 4, 128, 0, stream>>>(xq8, sq, wqkT, bqk, qkp, osg, osb, qq8, kq8, qs, ks);
  k_sim<<<dim3(32, B_), 256, 0, stream>>>(qq8, kq8, qs, ks, rel, aq8, as_);
  k_vmax<<<dim3(10, B_), 256, 0, stream>>>(v, vsmax);
  k_vq2<<<dim3(8, 10, B_), 256, 0, stream>>>(v, vsmax, vqt, vs);
  k_pv<<<dim3(32, B_), 256, 0, stream>>>(aq8, as_, vqt, vs, gate, out_s, oq8, osc);
  k_final<<<(NROW + 31) / 32, 256, 0, stream>>>(oq8, osc, woHi, woLo, bo, op, x, out);
}

// Round 4
// 289.589 us; speedup vs baseline: 3.8272x; 1.2588x over previous
//
#include <hip/hip_runtime.h>
#include <math.h>

#define B_   20
#define S_   500
#define DIM_ 300
#define QK_  128
#define HID_ 600
#define NROW (B_ * S_)   // 10000

typedef int   v4i    __attribute__((ext_vector_type(4)));
typedef short bf16x8 __attribute__((ext_vector_type(8)));
typedef short short4v __attribute__((ext_vector_type(4)));
typedef float f32x4  __attribute__((ext_vector_type(4)));

// ---- bf16 helpers (RNE) ----
__device__ __forceinline__ unsigned short f32_to_bf16(float f) {
  unsigned int u = __float_as_uint(f);
  unsigned int r = (u + 0x7FFFu + ((u >> 16) & 1u)) >> 16;
  return (unsigned short)r;
}
__device__ __forceinline__ float bf16_to_f32(unsigned short s) {
  return __uint_as_float(((unsigned int)s) << 16);
}

// T5 bucket: exact integer thresholds {12,16,23,32,46,64,91}; >=91 -> 15.
__device__ __forceinline__ int t5_bucket(int i, int j) {
  int d = i - j;
  int ret = (d < 0) ? 16 : 0;
  int n = d < 0 ? -d : d;
  int v;
  if (n < 8)       v = n;
  else if (n < 12) v = 8;
  else if (n < 16) v = 9;
  else if (n < 23) v = 10;
  else if (n < 32) v = 11;
  else if (n < 46) v = 12;
  else if (n < 64) v = 13;
  else if (n < 91) v = 14;
  else             v = 15;
  return ret + v;
}

__device__ __forceinline__ float quant15(float y, float s) {
  return truncf(fminf(fmaxf(__fdiv_rn(y, s), -15.f), 15.f));
}

// ---------- transpose (Wqk only): src[R][C] -> dst[C][R] ----------
__global__ __launch_bounds__(256) void k_transpose(const float* __restrict__ src,
                                                   float* __restrict__ dst,
                                                   int R, int C) {
  int idx = blockIdx.x * 256 + threadIdx.x;
  if (idx < R * C) {
    int r = idx / C, c = idx % C;
    dst[(size_t)c * R + r] = src[idx];
  }
}

// ---------- weight split: src[R][C] f32 -> hi/lo bf16 [RP][KP] ----------
__global__ __launch_bounds__(256) void k_wsplit(const float* __restrict__ src,
                                                unsigned short* __restrict__ hi,
                                                unsigned short* __restrict__ lo,
                                                int R, int C, int KP, int total) {
  int idx = blockIdx.x * 256 + threadIdx.x;
  if (idx >= total) return;
  int r = idx / KP, k = idx % KP;
  float val = (r < R && k < C) ? src[(size_t)r * C + k] : 0.f;
  unsigned short h = f32_to_bf16(val);
  float rem = val - bf16_to_f32(h);
  hi[idx] = h;
  lo[idx] = f32_to_bf16(rem);
}

// ---------- fused layernorm + token-shift + dual row-quant ----------
__global__ __launch_bounds__(256) void k_lnshift(
    const float* __restrict__ x,
    const float* __restrict__ g, const float* __restrict__ b,
    const float* __restrict__ qk_s, const float* __restrict__ hidden_s,
    signed char* __restrict__ xq8, signed char* __restrict__ xh8,
    float* __restrict__ sq, float* __restrict__ sh) {
  int row = blockIdx.x;
  int s_idx = row % S_;
  int tid = threadIdx.x;
  bool hasp = s_idx > 0;
  __shared__ float xc[DIM_], xp[DIM_];
  __shared__ float r1[256], r2[256];
  for (int c = tid; c < DIM_; c += 256) {
    xc[c] = x[(size_t)row * DIM_ + c];
    xp[c] = hasp ? x[(size_t)(row - 1) * DIM_ + c] : 0.f;
  }
  __syncthreads();
  // pass 1: means (identical reduction order to the validated k_ln)
  float sc = 0.f, sp = 0.f;
  for (int c = tid; c < DIM_; c += 256) { sc += xc[c]; sp += xp[c]; }
  r1[tid] = sc; r2[tid] = sp; __syncthreads();
  for (int off = 128; off > 0; off >>= 1) {
    if (tid < off) { r1[tid] += r1[tid + off]; r2[tid] += r2[tid + off]; }
    __syncthreads();
  }
  float mu_c = r1[0] / (float)DIM_;
  float mu_p = r2[0] / (float)DIM_;
  __syncthreads();
  // pass 2: variances
  float vc = 0.f, vp = 0.f;
  for (int c = tid; c < DIM_; c += 256) {
    float dc = xc[c] - mu_c; vc += dc * dc;
    float dp = xp[c] - mu_p; vp += dp * dp;
  }
  r1[tid] = vc; r2[tid] = vp; __syncthreads();
  for (int off = 128; off > 0; off >>= 1) {
    if (tid < off) { r1[tid] += r1[tid + off]; r2[tid] += r2[tid + off]; }
    __syncthreads();
  }
  float den_c = sqrtf(r1[0] / (float)DIM_ + 1e-5f);
  float den_p = sqrtf(r2[0] / (float)DIM_ + 1e-5f);
  __syncthreads();
  // shifted vector + dual quant
  float yq[2], yh[2];
  float mq = 0.f, mh = 0.f;
  #pragma unroll
  for (int it = 0; it < 2; ++it) {
    int c = tid + it * 256;
    if (c < DIM_) {
      float src;
      if (c < DIM_ / 2)
        src = hasp ? __fdiv_rn(xp[c] - mu_p, den_p) * g[c] + b[c] : 0.f;
      else
        src = __fdiv_rn(xc[c] - mu_c, den_c) * g[c] + b[c];
      yq[it] = __fdiv_rn(src, qk_s[c]);
      yh[it] = __fdiv_rn(src, hidden_s[c]);
      mq = fmaxf(mq, fabsf(yq[it]));
      mh = fmaxf(mh, fabsf(yh[it]));
    }
  }
  r1[tid] = mq; r2[tid] = mh; __syncthreads();
  for (int off = 128; off > 0; off >>= 1) {
    if (tid < off) {
      r1[tid] = fmaxf(r1[tid], r1[tid + off]);
      r2[tid] = fmaxf(r2[tid], r2[tid + off]);
    }
    __syncthreads();
  }
  float sqv = r1[0] / 15.0f, shv = r2[0] / 15.0f;
  if (tid == 0) { sq[row] = sqv; sh[row] = shv; }
  #pragma unroll
  for (int it = 0; it < 2; ++it) {
    int c = tid + it * 256;
    if (c < DIM_) {
      xq8[(size_t)row * DIM_ + c] = (signed char)quant15(yq[it], sqv);
      xh8[(size_t)row * DIM_ + c] = (signed char)quant15(yh[it], shv);
    }
  }
}

// ---------- kernel 3: hidden GEMM via bf16-split MFMA ----------
// 64 rows x 304 cols per block; grid (157, 4); 4 waves, wave w = 5 col-tiles.
#define KP_H  320
#define LDA_H 328
__global__ __launch_bounds__(256) void k_hidden(
    const signed char* __restrict__ xh8, const float* __restrict__ sh,
    const unsigned short* __restrict__ whHi, const unsigned short* __restrict__ whLo,
    const float* __restrict__ bh, const float* __restrict__ hp,
    float* __restrict__ v, float* __restrict__ gate) {
  int i0 = blockIdx.x * 64;
  int cg = blockIdx.y;           // col-group: cols cg*304 .. cg*304+303
  int tid = threadIdx.x;
  int w = tid >> 6, l = tid & 63, g = l >> 4, ln = l & 15;
  __shared__ unsigned short a_lds[64 * LDA_H];
  // stage A: 64 rows x 320 k (int8 -> bf16 exact)
  for (int idx = tid; idx < 64 * 80; idx += 256) {
    int r = idx / 80, kc = idx % 80;
    int grow = i0 + r; if (grow >= NROW) grow = NROW - 1;
    unsigned int u = 0;
    if (kc < 75) u = *(const unsigned int*)(xh8 + (size_t)grow * DIM_ + kc * 4);
    short4v st;
    st.x = (short)f32_to_bf16((float)(signed char)(u        & 0xff));
    st.y = (short)f32_to_bf16((float)(signed char)((u >> 8)  & 0xff));
    st.z = (short)f32_to_bf16((float)(signed char)((u >> 16) & 0xff));
    st.w = (short)f32_to_bf16((float)(signed char)((u >> 24) & 0xff));
    *(short4v*)&a_lds[r * LDA_H + kc * 4] = st;
  }
  __syncthreads();
  float sh_r[4][4];
  #pragma unroll
  for (int sl = 0; sl < 4; ++sl)
    #pragma unroll
    for (int r = 0; r < 4; ++r) {
      int grow = i0 + sl * 16 + g * 4 + r;
      sh_r[sl][r] = sh[grow < NROW ? grow : NROW - 1];
    }
  for (int t = 0; t < 5; ++t) {
    int tt = w * 5 + t;
    if (tt >= 19) break;                 // 19 tiles cover 304 cols
    int j0 = cg * 304 + tt * 16;
    const unsigned short* bhp = whHi + (size_t)(j0 + ln) * KP_H + g * 8;
    const unsigned short* blp = whLo + (size_t)(j0 + ln) * KP_H + g * 8;
    f32x4 acc[4];
    #pragma unroll
    for (int sl = 0; sl < 4; ++sl) acc[sl] = (f32x4){0.f, 0.f, 0.f, 0.f};
    #pragma unroll
    for (int kk = 0; kk < 10; ++kk) {
      bf16x8 bhv = *(const bf16x8*)(bhp + kk * 32);
      bf16x8 blv = *(const bf16x8*)(blp + kk * 32);
      #pragma unroll
      for (int sl = 0; sl < 4; ++sl) {
        bf16x8 a = *(const bf16x8*)&a_lds[(sl * 16 + ln) * LDA_H + kk * 32 + g * 8];
        acc[sl] = __builtin_amdgcn_mfma_f32_16x16x32_bf16(a, bhv, acc[sl], 0, 0, 0);
        acc[sl] = __builtin_amdgcn_mfma_f32_16x16x32_bf16(a, blv, acc[sl], 0, 0, 0);
      }
    }
    int col = j0 + ln;
    if (col < 2 * HID_) {
      float bc = bh[col], hpc = hp[col];
      #pragma unroll
      for (int sl = 0; sl < 4; ++sl) {
        #pragma unroll
        for (int r = 0; r < 4; ++r) {
          int grow = i0 + sl * 16 + g * 4 + r;
          if (grow < NROW) {
            float z = acc[sl][r] + bc;
            float sig = 1.0f / (1.0f + __expf(-z));
            float val = __fmul_rn(z * sig, __fmul_rn(sh_r[sl][r], hpc));
            if (col < HID_) v[(size_t)grow * HID_ + col] = val;
            else            gate[(size_t)grow * HID_ + (col - HID_)] = val;
          }
        }
      }
    }
  }
}

// ---------- kernel 4: qk GEMM (W^T, 4 rows/block) + silu + rotary + quant ----------
__global__ __launch_bounds__(128) void k_qk(
    const signed char* __restrict__ xq8, const float* __restrict__ sq,
    const float* __restrict__ wqkT,   // [300][128]
    const float* __restrict__ bqk,
    const float* __restrict__ qkp, const float* __restrict__ osg,
    const float* __restrict__ osb,
    signed char* __restrict__ qq8, signed char* __restrict__ kq8,
    float* __restrict__ qs, float* __restrict__ ks) {
  int row0 = blockIdx.x * 4;
  int c = threadIdx.x;   // 0..127
  __shared__ float xs[4][DIM_];
  __shared__ float qbuf[4][QK_], kbuf[4][QK_];
  __shared__ float redq[4][QK_], redk[4][QK_];
  for (int idx = c; idx < 4 * DIM_; idx += 128) {
    int r = idx / DIM_, cc = idx % DIM_;
    xs[r][cc] = (float)xq8[(size_t)(row0 + r) * DIM_ + cc];
  }
  __syncthreads();
  float acc[4] = {0.f, 0.f, 0.f, 0.f};
  for (int k = 0; k < DIM_; ++k) {
    float w = wqkT[k * QK_ + c];
    #pragma unroll
    for (int r = 0; r < 4; ++r) acc[r] += xs[r][k] * w;
  }
  float bc = bqk[c], qkpc = qkp[c];
  float g0 = osg[c], g1 = osg[QK_ + c], b0 = osb[c], b1 = osb[QK_ + c];
  float qv[4], kv[4];
  #pragma unroll
  for (int r = 0; r < 4; ++r) {
    float z = acc[r] + bc;
    float sig = 1.0f / (1.0f + expf(-z));
    float qkv = __fmul_rn(z * sig, __fmul_rn(sq[row0 + r], qkpc));
    qv[r] = __fadd_rn(__fmul_rn(qkv, g0), b0);
    kv[r] = __fadd_rn(__fmul_rn(qkv, g1), b1);
    qbuf[r][c] = qv[r]; kbuf[r][c] = kv[r];
  }
  __syncthreads();
  if (c < 32) {
    double e = (double)(c & ~1) / 32.0;
    float inv = (float)(1.0 / pow(10000.0, e));
    #pragma unroll
    for (int r = 0; r < 4; ++r) {
      int pos = (row0 + r) % S_;
      float fr = __fmul_rn((float)pos, inv);
      float cs = cosf(fr), sn = sinf(fr);
      float rq = ((c & 1) == 0) ? -qbuf[r][c + 1] : qbuf[r][c - 1];
      float rk = ((c & 1) == 0) ? -kbuf[r][c + 1] : kbuf[r][c - 1];
      qv[r] = __fadd_rn(__fmul_rn(qv[r], cs), __fmul_rn(rq, sn));
      kv[r] = __fadd_rn(__fmul_rn(kv[r], cs), __fmul_rn(rk, sn));
    }
  }
  #pragma unroll
  for (int r = 0; r < 4; ++r) { redq[r][c] = fabsf(qv[r]); redk[r][c] = fabsf(kv[r]); }
  __syncthreads();
  for (int off = 64; off > 0; off >>= 1) {
    if (c < off) {
      #pragma unroll
      for (int r = 0; r < 4; ++r) {
        redq[r][c] = fmaxf(redq[r][c], redq[r][c + off]);
        redk[r][c] = fmaxf(redk[r][c], redk[r][c + off]);
      }
    }
    __syncthreads();
  }
  #pragma unroll
  for (int r = 0; r < 4; ++r) {
    float qsv = redq[r][0] / 15.0f, ksv = redk[r][0] / 15.0f;
    if (c == 0) { qs[row0 + r] = qsv; ks[row0 + r] = ksv; }
    qq8[(size_t)(row0 + r) * QK_ + c] = (signed char)quant15(qv[r], qsv);
    kq8[(size_t)(row0 + r) * QK_ + c] = (signed char)quant15(kv[r], ksv);
  }
}

// ---------- kernel 5: MFMA i8 QK^T + T5 bias + relu^2 + row-quant ----------
__global__ __launch_bounds__(256) void k_sim(
    const signed char* __restrict__ qq8, const signed char* __restrict__ kq8,
    const float* __restrict__ qs, const float* __restrict__ ks,
    const float* __restrict__ rel_emb,
    signed char* __restrict__ aq8, float* __restrict__ as_) {
  int i0 = blockIdx.x * 16;
  int b = blockIdx.y;
  int tid = threadIdx.x;
  int w = tid >> 6, l = tid & 63, g = l >> 4, ln = l & 15;
  __shared__ __align__(16) signed char a_lds[16 * 144];
  __shared__ float rel[32];
  __shared__ int rowmax[16];
  if (tid < 128) {
    int r = tid >> 3, ww = tid & 7;
    *(v4i*)(a_lds + r * 144 + ww * 16) =
        *(const v4i*)(qq8 + ((size_t)(b * S_ + i0 + r)) * QK_ + ww * 16);
  }
  if (tid < 32) rel[tid] = rel_emb[tid];
  if (tid < 16) rowmax[tid] = 0;
  __syncthreads();
  v4i acc[8];
  v4i zero = {0, 0, 0, 0};
  #pragma unroll
  for (int t = 0; t < 8; ++t) acc[t] = zero;
  #pragma unroll
  for (int kk = 0; kk < 2; ++kk) {
    v4i afrag = *(const v4i*)(a_lds + ln * 144 + kk * 64 + g * 16);
    #pragma unroll
    for (int t = 0; t < 8; ++t) {
      int j0 = (w * 8 + t) * 16;
      v4i bfrag = *(const v4i*)(kq8 + ((size_t)(b * S_ + j0 + ln)) * QK_ + kk * 64 + g * 16);
      acc[t] = __builtin_amdgcn_mfma_i32_16x16x64_i8(afrag, bfrag, acc[t], 0, 0, 0);
    }
  }
  float qsr[4];
  #pragma unroll
  for (int r = 0; r < 4; ++r) qsr[r] = qs[b * S_ + i0 + g * 4 + r];
  float rm[4] = {0.f, 0.f, 0.f, 0.f};
  #pragma unroll
  for (int t = 0; t < 8; ++t) {
    int j = (w * 8 + t) * 16 + ln;
    bool jv = j < S_;
    float ksv = ks[b * S_ + j];
    #pragma unroll
    for (int r = 0; r < 4; ++r) {
      int ip = i0 + g * 4 + r;
      float av = 0.f;
      if (jv) {
        float simv = __fmul_rn(__fmul_rn((float)acc[t][r], qsr[r]), ksv);
        simv = __fadd_rn(simv, __fmul_rn(rel[t5_bucket(ip, j)], 11.313708498984761f));
        float rr = fmaxf(__fdiv_rn(simv, 500.0f), 0.f);
        av = __fmul_rn(rr, rr);
      }
      rm[r] = fmaxf(rm[r], av);
      acc[t][r] = __float_as_int(av);
    }
  }
  #pragma unroll
  for (int r = 0; r < 4; ++r) atomicMax(&rowmax[g * 4 + r], __float_as_int(rm[r]));
  __syncthreads();
  #pragma unroll
  for (int r = 0; r < 4; ++r) qsr[r] = __int_as_float(rowmax[g * 4 + r]) / 15.0f;
  #pragma unroll
  for (int t = 0; t < 8; ++t) {
    int j = (w * 8 + t) * 16 + ln;
    #pragma unroll
    for (int r = 0; r < 4; ++r) {
      int ip = i0 + g * 4 + r;
      if (ip < S_)
        aq8[((size_t)b * S_ + ip) * 512 + j] =
            (j < S_) ? (signed char)quant15(__int_as_float(acc[t][r]), qsr[r])
                     : (signed char)0;
    }
  }
  if (tid < 16 && i0 + tid < S_)
    as_[b * S_ + i0 + tid] = __int_as_float(rowmax[tid]) / 15.0f;
}

// ---------- kernel 6a: per-(b,d) max over s (coalesced) ----------
__global__ __launch_bounds__(256) void k_vmax(const float* __restrict__ v,
                                              int* __restrict__ vsmax) {
  int b = blockIdx.y;
  int s0 = blockIdx.x * 25;
  int tid = threadIdx.x;
  float m[3] = {0.f, 0.f, 0.f};
  for (int s = s0; s < s0 + 25; ++s) {
    const float* vp = v + ((size_t)b * S_ + s) * HID_;
    #pragma unroll
    for (int it = 0; it < 3; ++it) {
      int d = tid + it * 256;
      if (d < HID_) m[it] = fmaxf(m[it], fabsf(vp[d]));
    }
  }
  #pragma unroll
  for (int it = 0; it < 3; ++it) {
    int d = tid + it * 256;
    if (d < HID_) atomicMax(&vsmax[b * 640 + d], __float_as_int(m[it]));
  }
}

// ---------- kernel 6b: quantize+transpose v (64x64 LDS tiles) ----------
__global__ __launch_bounds__(256) void k_vq2(const float* __restrict__ v,
                                             const int* __restrict__ vsmax,
                                             signed char* __restrict__ vqt,  // [B][640][512]
                                             float* __restrict__ vs) {       // [B][640]
  int b = blockIdx.z;
  int s0 = blockIdx.x * 64;
  int d0 = blockIdx.y * 64;
  __shared__ float tile[64][65];
  int tid = threadIdx.x;
  int dj = tid & 63, si4 = tid >> 6;
  #pragma unroll
  for (int it = 0; it < 16; ++it) {
    int s = s0 + it * 4 + si4;
    int d = d0 + dj;
    float val = 0.f;
    if (s < S_ && d < HID_) val = v[((size_t)b * S_ + s) * HID_ + d];
    tile[it * 4 + si4][dj] = val;
  }
  if (blockIdx.x == 0 && tid < 64 && d0 + tid < HID_)
    vs[b * 640 + d0 + tid] = __int_as_float(vsmax[b * 640 + d0 + tid]) / 15.0f;
  __syncthreads();
  int dd = tid >> 2, seg = tid & 3;
  int d = d0 + dd;
  if (d < HID_) {
    float vsv = __int_as_float(vsmax[b * 640 + d]) / 15.0f;
    v4i pack;
    signed char* pc = (signed char*)&pack;
    #pragma unroll
    for (int e = 0; e < 16; ++e)
      pc[e] = (signed char)quant15(tile[seg * 16 + e][dd], vsv);
    *(v4i*)(vqt + ((size_t)b * 640 + d) * 512 + s0 + seg * 16) = pack;
  }
}

// ---------- kernel 7: MFMA i8 PV + gate + /out_s + row-quant ----------
__global__ __launch_bounds__(256) void k_pv(
    const signed char* __restrict__ aq8, const float* __restrict__ as_,
    const signed char* __restrict__ vqt, const float* __restrict__ vs,
    const float* __restrict__ gate, const float* __restrict__ out_s,
    signed char* __restrict__ oq8, float* __restrict__ osc) {
  int i0 = blockIdx.x * 16;
  int b = blockIdx.y;
  int tid = threadIdx.x;
  int w = tid >> 6, l = tid & 63, g = l >> 4, ln = l & 15;
  __shared__ __align__(16) signed char a_lds[16 * 528];
  __shared__ int rowmax[16];
  #pragma unroll
  for (int rep = 0; rep < 2; ++rep) {
    int linear = rep * 256 + tid;
    int r = linear >> 5, ww = linear & 31;
    *(v4i*)(a_lds + r * 528 + ww * 16) =
        *(const v4i*)(aq8 + ((size_t)(b * S_ + i0 + r)) * 512 + ww * 16);
  }
  if (tid < 16) rowmax[tid] = 0;
  __syncthreads();
  v4i acc[10];
  v4i zero = {0, 0, 0, 0};
  #pragma unroll
  for (int t = 0; t < 10; ++t) acc[t] = zero;
  for (int kk = 0; kk < 8; ++kk) {
    v4i afrag = *(const v4i*)(a_lds + ln * 528 + kk * 64 + g * 16);
    #pragma unroll
    for (int t = 0; t < 10; ++t) {
      int d0 = (w * 10 + t) * 16;
      v4i bfrag = *(const v4i*)(vqt + ((size_t)b * 640 + d0 + ln) * 512 + kk * 64 + g * 16);
      acc[t] = __builtin_amdgcn_mfma_i32_16x16x64_i8(afrag, bfrag, acc[t], 0, 0, 0);
    }
  }
  float asr[4];
  #pragma unroll
  for (int r = 0; r < 4; ++r) asr[r] = as_[b * S_ + i0 + g * 4 + r];
  float rm[4] = {0.f, 0.f, 0.f, 0.f};
  #pragma unroll
  for (int t = 0; t < 10; ++t) {
    int d = (w * 10 + t) * 16 + ln;
    bool dv = d < HID_;
    float vsv = vs[b * 640 + d];
    float outs = dv ? out_s[d] : 1.0f;
    #pragma unroll
    for (int r = 0; r < 4; ++r) {
      int grow = b * S_ + i0 + g * 4 + r;
      float o = 0.f;
      if (dv) {
        o = __fmul_rn(__fmul_rn((float)acc[t][r], asr[r]), vsv);
        o = __fmul_rn(o, gate[(size_t)grow * HID_ + d]);
        o = __fdiv_rn(o, outs);
      }
      rm[r] = fmaxf(rm[r], fabsf(o));
      acc[t][r] = __float_as_int(o);
    }
  }
  #pragma unroll
  for (int r = 0; r < 4; ++r) atomicMax(&rowmax[g * 4 + r], __float_as_int(rm[r]));
  __syncthreads();
  #pragma unroll
  for (int r = 0; r < 4; ++r) asr[r] = __int_as_float(rowmax[g * 4 + r]) / 15.0f;
  #pragma unroll
  for (int t = 0; t < 10; ++t) {
    int d = (w * 10 + t) * 16 + ln;
    #pragma unroll
    for (int r = 0; r < 4; ++r) {
      int il = i0 + g * 4 + r;
      if (d < HID_ && il < S_)
        oq8[((size_t)b * S_ + il) * 608 + d] =
            (signed char)quant15(__int_as_float(acc[t][r]), asr[r]);
    }
  }
  if (tid < 16 && i0 + tid < S_)
    osc[b * S_ + i0 + tid] = __int_as_float(rowmax[tid]) / 15.0f;
}

// ---------- kernel 8: output GEMM via bf16-split MFMA + residual ----------
// 32 rows/block, col-split by 2: grid (313, 2).
#define KP_F  608
#define LDA_F 616
__global__ __launch_bounds__(256) void k_final(
    const signed char* __restrict__ oq8,   // [NROW][608]
    const float* __restrict__ osc,
    const unsigned short* __restrict__ woHi, const unsigned short* __restrict__ woLo,
    const float* __restrict__ bo, const float* __restrict__ op,
    const float* __restrict__ x, float* __restrict__ out) {
  int i0 = blockIdx.x * 32;
  int by = blockIdx.y;
  int tid = threadIdx.x;
  int w = tid >> 6, l = tid & 63, g = l >> 4, ln = l & 15;
  __shared__ unsigned short a_lds[32 * LDA_F];
  for (int idx = tid; idx < 32 * 152; idx += 256) {
    int r = idx / 152, kc = idx % 152;
    int grow = i0 + r; if (grow >= NROW) grow = NROW - 1;
    unsigned int u = *(const unsigned int*)(oq8 + (size_t)grow * 608 + kc * 4);
    short4v st;
    st.x = (short)f32_to_bf16((float)(signed char)(u        & 0xff));
    st.y = (short)f32_to_bf16((float)(signed char)((u >> 8)  & 0xff));
    st.z = (short)f32_to_bf16((float)(signed char)((u >> 16) & 0xff));
    st.w = (short)f32_to_bf16((float)(signed char)((u >> 24) & 0xff));
    *(short4v*)&a_lds[r * LDA_F + kc * 4] = st;
  }
  __syncthreads();
  float osc_r[2][4];
  #pragma unroll
  for (int sl = 0; sl < 2; ++sl)
    #pragma unroll
    for (int r = 0; r < 4; ++r) {
      int grow = i0 + sl * 16 + g * 4 + r;
      osc_r[sl][r] = osc[grow < NROW ? grow : NROW - 1];
    }
  int tstart = by * 10;
  int tend = (by == 0) ? 10 : 19;
  for (int t = tstart + w; t < tend; t += 4) {
    int j0 = t * 16;
    const unsigned short* bhp = woHi + (size_t)(j0 + ln) * KP_F + g * 8;
    const unsigned short* blp = woLo + (size_t)(j0 + ln) * KP_F + g * 8;
    f32x4 acc0 = {0.f, 0.f, 0.f, 0.f}, acc1 = {0.f, 0.f, 0.f, 0.f};
    for (int kk = 0; kk < 19; ++kk) {
      bf16x8 a0 = *(const bf16x8*)&a_lds[ln * LDA_F + kk * 32 + g * 8];
      bf16x8 a1 = *(const bf16x8*)&a_lds[(16 + ln) * LDA_F + kk * 32 + g * 8];
      bf16x8 bhv = *(const bf16x8*)(bhp + kk * 32);
      bf16x8 blv = *(const bf16x8*)(blp + kk * 32);
      acc0 = __builtin_amdgcn_mfma_f32_16x16x32_bf16(a0, bhv, acc0, 0, 0, 0);
      acc0 = __builtin_amdgcn_mfma_f32_16x16x32_bf16(a0, blv, acc0, 0, 0, 0);
      acc1 = __builtin_amdgcn_mfma_f32_16x16x32_bf16(a1, bhv, acc1, 0, 0, 0);
      acc1 = __builtin_amdgcn_mfma_f32_16x16x32_bf16(a1, blv, acc1, 0, 0, 0);
    }
    int col = j0 + ln;
    if (col < DIM_) {
      float bc = bo[col], opc = op[col];
      #pragma unroll
      for (int sl = 0; sl < 2; ++sl) {
        #pragma unroll
        for (int r = 0; r < 4; ++r) {
          int grow = i0 + sl * 16 + g * 4 + r;
          if (grow < NROW) {
            float tval = __fmul_rn(osc_r[sl][r], opc);
            float res = __fmul_rn((sl ? acc1[r] : acc0[r]) + bc, tval);
            out[(size_t)grow * DIM_ + col] = res + x[(size_t)grow * DIM_ + col];
          }
        }
      }
    }
  }
}

// ---------- launch ----------
extern "C" void kernel_launch(void* const* d_in, const int* in_sizes, int n_in,
                              void* d_out, int out_size, void* d_ws, size_t ws_size,
                              hipStream_t stream) {
  const float* x        = (const float*)d_in[0];
  const float* ng       = (const float*)d_in[1];
  const float* nbt      = (const float*)d_in[2];
  const float* Wh       = (const float*)d_in[3];
  const float* bh       = (const float*)d_in[4];
  const float* Wqk      = (const float*)d_in[5];
  const float* bqk      = (const float*)d_in[6];
  const float* osg      = (const float*)d_in[7];
  const float* osb      = (const float*)d_in[8];
  const float* Wo       = (const float*)d_in[9];
  const float* bo       = (const float*)d_in[10];
  const float* rel      = (const float*)d_in[11];
  const float* qk_s     = (const float*)d_in[12];
  const float* hidden_s = (const float*)d_in[13];
  const float* out_s    = (const float*)d_in[14];
  const float* hp       = (const float*)d_in[15];
  const float* qkp      = (const float*)d_in[16];
  const float* op       = (const float*)d_in[17];
  float* out = (float*)d_out;

  char* ws = (char*)d_ws;
  size_t off = 0;
  auto alloc = [&](size_t bytes) {
    void* p = ws + off;
    off += (bytes + 255) & ~(size_t)255;
    return p;
  };
  signed char* xq8    = (signed char*)alloc((size_t)NROW * DIM_);
  signed char* xh8    = (signed char*)alloc((size_t)NROW * DIM_);
  float*       sq     = (float*)      alloc((size_t)(NROW + 64) * 4);
  float*       sh     = (float*)      alloc((size_t)(NROW + 64) * 4);
  float*       v      = (float*)      alloc((size_t)NROW * HID_ * 4);
  float*       gate   = (float*)      alloc((size_t)(NROW + 64) * HID_ * 4);
  signed char* qq8    = (signed char*)alloc((size_t)(NROW + 16) * QK_);
  signed char* kq8    = (signed char*)alloc((size_t)(NROW + 16) * QK_);
  float*       qs     = (float*)      alloc((size_t)(NROW + 16) * 4);
  float*       ks     = (float*)      alloc((size_t)(NROW + 16) * 4);
  signed char* aq8    = (signed char*)alloc((size_t)(NROW + 16) * 512);
  float*       as_    = (float*)      alloc((size_t)(NROW + 16) * 4);
  signed char* vqt    = (signed char*)alloc((size_t)B_ * 640 * 512);
  float*       vs     = (float*)      alloc((size_t)B_ * 640 * 4);
  int*         vsmax  = (int*)        alloc((size_t)B_ * 640 * 4);
  signed char* oq8    = (signed char*)alloc((size_t)NROW * 608);
  float*       osc    = (float*)      alloc((size_t)(NROW + 64) * 4);
  unsigned short* whHi = (unsigned short*)alloc((size_t)1216 * KP_H * 2);
  unsigned short* whLo = (unsigned short*)alloc((size_t)1216 * KP_H * 2);
  unsigned short* woHi = (unsigned short*)alloc((size_t)304 * KP_F * 2);
  unsigned short* woLo = (unsigned short*)alloc((size_t)304 * KP_F * 2);
  float*       wqkT   = (float*)      alloc((size_t)DIM_ * QK_ * 4);

  hipMemsetAsync(vsmax, 0, (size_t)B_ * 640 * 4, stream);

  k_wsplit<<<(1216 * KP_H + 255) / 256, 256, 0, stream>>>(Wh, whHi, whLo,
                                                          2 * HID_, DIM_, KP_H, 1216 * KP_H);
  k_wsplit<<<(304 * KP_F + 255) / 256, 256, 0, stream>>>(Wo, woHi, woLo,
                                                         DIM_, HID_, KP_F, 304 * KP_F);
  k_transpose<<<(QK_ * DIM_ + 255) / 256, 256, 0, stream>>>(Wqk, wqkT, QK_, DIM_);

  k_lnshift<<<NROW, 256, 0, stream>>>(x, ng, nbt, qk_s, hidden_s, xq8, xh8, sq, sh);
  k_hidden<<<dim3(157, 4), 256, 0, stream>>>(xh8, sh, whHi, whLo, bh, hp, v, gate);
  k_qk<<<NROW / 4, 128, 0, stream>>>(xq8, sq, wqkT, bqk, qkp, osg, osb, qq8, kq8, qs, ks);
  k_sim<<<dim3(32, B_), 256, 0, stream>>>(qq8, kq8, qs, ks, rel, aq8, as_);
  k_vmax<<<dim3(20, B_), 256, 0, stream>>>(v, vsmax);
  k_vq2<<<dim3(8, 10, B_), 256, 0, stream>>>(v, vsmax, vqt, vs);
  k_pv<<<dim3(32, B_), 256, 0, stream>>>(aq8, as_, vqt, vs, gate, out_s, oq8, osc);
  k_final<<<dim3(313, 2), 256, 0, stream>>>(oq8, osc, woHi, woLo, bo, op, x, out);
}